// Round 4
// baseline (2453.163 us; speedup 1.0000x reference)
//
#include <hip/hip_runtime.h>
#include <hip/hip_bf16.h>
#include <hip/hip_fp16.h>
#include <math.h>

// SportsGNN: ftMLP -> GATv2 x2 -> sumpool -> MLP -> softmax
// N=250000, E=5000000, H=2, O=8 (HO=16)
// Strategy: bucket partition (256 dst nodes/bucket) of packed 8B edge records,
// then per-bucket in-LDS bin sort fused with per-(node,head) online-softmax
// aggregation. No global fine-grained scatter, no global CSR, no float atomics.

#define HO 16
#define BSHIFT 8
#define BNODES 256          // nodes per bucket (1 << BSHIFT)
#define CAP 8192            // max records per bucket held in LDS (mean ~5.1k)

__device__ __forceinline__ float lrelu(float x, float s) { return x > 0.f ? x : s * x; }

// ---------------- node kernel, layer 1: x[N,3] -> ftMLP -> xl1,xr1 [N,16] ----------------
__global__ void __launch_bounds__(256) node_l1(
    const float* __restrict__ x,
    const float* __restrict__ ft1_w, const float* __restrict__ ft1_b,
    const float* __restrict__ ft2_w, const float* __restrict__ ft2_b,
    const float* __restrict__ wl, const float* __restrict__ bl,
    const float* __restrict__ wr, const float* __restrict__ br,
    float* __restrict__ xl, float* __restrict__ xr, int N)
{
    int n = blockIdx.x * 256 + threadIdx.x;
    if (n >= N) return;
    float x0 = x[3*n], x1 = x[3*n+1], x2 = x[3*n+2];
    float h1[8];
#pragma unroll
    for (int j = 0; j < 8; j++) {
        float a = ft1_w[3*j]*x0 + ft1_w[3*j+1]*x1 + ft1_w[3*j+2]*x2 + ft1_b[j];
        h1[j] = lrelu(a, 0.1f);
    }
    float h2[8];
#pragma unroll
    for (int j = 0; j < 8; j++) {
        float a = ft2_b[j];
#pragma unroll
        for (int k = 0; k < 8; k++) a += ft2_w[8*j+k]*h1[k];
        h2[j] = lrelu(a, 0.1f);
    }
    float ol[HO], orr[HO];
#pragma unroll
    for (int j = 0; j < HO; j++) {
        float a = bl[j], b = br[j];
#pragma unroll
        for (int k = 0; k < 8; k++) { a += wl[8*j+k]*h2[k]; b += wr[8*j+k]*h2[k]; }
        ol[j] = a; orr[j] = b;
    }
    float4* xl4 = (float4*)(xl + (size_t)n*HO);
    float4* xr4 = (float4*)(xr + (size_t)n*HO);
#pragma unroll
    for (int q = 0; q < 4; q++) {
        xl4[q] = make_float4(ol[4*q], ol[4*q+1], ol[4*q+2], ol[4*q+3]);
        xr4[q] = make_float4(orr[4*q], orr[4*q+1], orr[4*q+2], orr[4*q+3]);
    }
}

// ---------------- bucket build ----------------
__global__ void __launch_bounds__(256) k_bhist(
    const int* __restrict__ dst, int* __restrict__ bcnt, int E)
{
    int e = blockIdx.x * 256 + threadIdx.x;
    if (e < E) atomicAdd(&bcnt[dst[e] >> BSHIFT], 1);
}

// exclusive scan of bucket counts (nb <= 1024); writes boff (and boff[nb]=E) + bcur
__global__ void __launch_bounds__(1024) k_bscan(
    const int* __restrict__ bcnt, int* __restrict__ boff, int* __restrict__ bcur,
    int nb, int E)
{
    __shared__ int s[1024];
    int t = threadIdx.x;
    int v = (t < nb) ? bcnt[t] : 0;
    s[t] = v;
    __syncthreads();
    for (int off = 1; off < 1024; off <<= 1) {
        int a = (t >= off) ? s[t - off] : 0;
        __syncthreads();
        s[t] += a;
        __syncthreads();
    }
    if (t < nb) { int ex = s[t] - v; boff[t] = ex; bcur[t] = ex; }
    if (t == 0) boff[nb] = E;
}

// append packed records into bucket ranges: rec.x = (src<<8)|(dst&255), rec.y = half2(eattr)
__global__ void __launch_bounds__(256) k_bscatter(
    const int* __restrict__ src, const int* __restrict__ dst,
    const float* __restrict__ eattr, int* __restrict__ bcur,
    uint2* __restrict__ grecs, int E)
{
    int e = blockIdx.x * 256 + threadIdx.x;
    if (e >= E) return;
    int d = dst[e];
    int b = d >> BSHIFT;
    int pos = atomicAdd(&bcur[b], 1);
    float2 ea = ((const float2*)eattr)[e];
    __half2 hv = __floats2half2_rn(ea.x, ea.y);
    unsigned int eb = *reinterpret_cast<unsigned int*>(&hv);
    grecs[pos] = make_uint2(((unsigned int)src[e] << 8) | (unsigned int)(d & (BNODES-1)), eb);
}

// ---------------- online-softmax per-edge update ----------------
struct AggState { float m, s, acc[8]; };

__device__ __forceinline__ void agg_edge(
    AggState& st, const float* va, const float* xd,
    const float* w0, const float* w1, const float* at,
    float ea0, float ea1)
{
    float lg = 0.f;
#pragma unroll
    for (int o = 0; o < 8; o++) {
        float mv = va[o] + xd[o] + (w0[o]*ea0 + w1[o]*ea1);
        mv = mv > 0.f ? mv : 0.2f*mv;      // leaky_relu 0.2
        lg += mv * at[o];
    }
    float nm = fmaxf(st.m, lg);
    float sc = __expf(st.m - nm);
    float wv = __expf(lg - nm);
    st.s = st.s*sc + wv;
#pragma unroll
    for (int o = 0; o < 8; o++) st.acc[o] = st.acc[o]*sc + wv*va[o];
    st.m = nm;
}

// in-LDS bucket bin-sort: fills srec (sorted by local dst), scnt (counts), soff (inclusive scan)
__device__ __forceinline__ void bucket_sort_stage(
    const uint2* __restrict__ grecs, const int* __restrict__ boff,
    uint2* srec, int* scnt, int* soff, int* scur)
{
    int b = blockIdx.x;
    int gbeg = boff[b], gend = boff[b+1];
    int cnt = gend - gbeg;
    if (cnt > CAP) cnt = CAP;   // safety clamp; 43-sigma margin on uniform input
    int t = threadIdx.x;
    if (t < BNODES) scnt[t] = 0;
    __syncthreads();
    for (int i = t; i < cnt; i += 512) {
        uint2 r = grecs[gbeg + i];
        atomicAdd(&scnt[r.x & (BNODES-1)], 1);
    }
    __syncthreads();
    if (t < BNODES) soff[t] = scnt[t];
    __syncthreads();
    for (int off = 1; off < BNODES; off <<= 1) {
        int v = 0;
        if (t < BNODES && t >= off) v = soff[t - off];
        __syncthreads();
        if (t < BNODES) soff[t] += v;       // inclusive scan
        __syncthreads();
    }
    if (t < BNODES) scur[t] = soff[t] - scnt[t];   // exclusive start
    __syncthreads();
    for (int i = t; i < cnt; i += 512) {
        uint2 r = grecs[gbeg + i];
        int pos = atomicAdd(&scur[r.x & (BNODES-1)], 1);
        srec[pos] = r;
    }
    __syncthreads();
}

// per-(node,head) aggregation out of sorted LDS records
__device__ __forceinline__ void agg_from_lds(
    int nl, int h, const uint2* srec, const int* scnt, const int* soff,
    int n, const float* __restrict__ xl, const float* __restrict__ xr,
    const float* __restrict__ we, const float* __restrict__ att,
    const float* __restrict__ bias, float* out)
{
    int kb = h*8;
    float xd[8], w0[8], w1[8], at[8];
    {
        const float4* xrp = (const float4*)(xr + (size_t)n*HO + kb);
        float4 d0 = xrp[0], d1 = xrp[1];
        xd[0]=d0.x; xd[1]=d0.y; xd[2]=d0.z; xd[3]=d0.w;
        xd[4]=d1.x; xd[5]=d1.y; xd[6]=d1.z; xd[7]=d1.w;
    }
#pragma unroll
    for (int o = 0; o < 8; o++) {
        w0[o] = we[2*(kb+o)];
        w1[o] = we[2*(kb+o)+1];
        at[o] = att[kb+o];
    }
    AggState st;
    st.m = -INFINITY; st.s = 0.f;
#pragma unroll
    for (int o = 0; o < 8; o++) st.acc[o] = 0.f;

    int end = soff[nl], i = end - scnt[nl];
    for (; i + 2 <= end; i += 2) {
        uint2 rA = srec[i], rB = srec[i+1];
        int sA = rA.x >> 8, sB = rB.x >> 8;
        const float4* pA = (const float4*)(xl + (size_t)sA*HO + kb);
        const float4* pB = (const float4*)(xl + (size_t)sB*HO + kb);
        float4 a0 = pA[0], a1 = pA[1];
        float4 b0 = pB[0], b1 = pB[1];
        __half2 hA = *reinterpret_cast<__half2*>(&rA.y);
        __half2 hB = *reinterpret_cast<__half2*>(&rB.y);
        float vA[8] = {a0.x,a0.y,a0.z,a0.w,a1.x,a1.y,a1.z,a1.w};
        float vB[8] = {b0.x,b0.y,b0.z,b0.w,b1.x,b1.y,b1.z,b1.w};
        agg_edge(st, vA, xd, w0, w1, at, __low2float(hA), __high2float(hA));
        agg_edge(st, vB, xd, w0, w1, at, __low2float(hB), __high2float(hB));
    }
    if (i < end) {
        uint2 rA = srec[i];
        int sA = rA.x >> 8;
        const float4* pA = (const float4*)(xl + (size_t)sA*HO + kb);
        float4 a0 = pA[0], a1 = pA[1];
        __half2 hA = *reinterpret_cast<__half2*>(&rA.y);
        float vA[8] = {a0.x,a0.y,a0.z,a0.w,a1.x,a1.y,a1.z,a1.w};
        agg_edge(st, vA, xd, w0, w1, at, __low2float(hA), __high2float(hA));
    }
    float inv = 1.f/(st.s + 1e-16f);
#pragma unroll
    for (int o = 0; o < 8; o++) out[o] = st.acc[o]*inv + bias[kb+o];
}

// layer 1: bucket sort + aggregate + lrelu(0.1) -> hout
__global__ void __launch_bounds__(512) agg_l1(
    const uint2* __restrict__ grecs, const int* __restrict__ boff,
    const float* __restrict__ xl, const float* __restrict__ xr,
    const float* __restrict__ we, const float* __restrict__ att,
    const float* __restrict__ bias, float* __restrict__ hout, int N)
{
    __shared__ uint2 srec[CAP];
    __shared__ int scnt[BNODES], soff[BNODES], scur[BNODES];
    bucket_sort_stage(grecs, boff, srec, scnt, soff, scur);
    int t = threadIdx.x;
    int nl = t >> 1, h = t & 1;
    int n = blockIdx.x * BNODES + nl;
    if (n >= N) return;
    float out[8];
    agg_from_lds(nl, h, srec, scnt, soff, n, xl, xr, we, att, bias, out);
    float4* hp = (float4*)(hout + (size_t)n*HO + h*8);
    hp[0] = make_float4(lrelu(out[0],0.1f), lrelu(out[1],0.1f), lrelu(out[2],0.1f), lrelu(out[3],0.1f));
    hp[1] = make_float4(lrelu(out[4],0.1f), lrelu(out[5],0.1f), lrelu(out[6],0.1f), lrelu(out[7],0.1f));
}

// layer 2: bucket sort + aggregate (+bias), block-reduce -> partials[16] per block
__global__ void __launch_bounds__(512) agg_l2(
    const uint2* __restrict__ grecs, const int* __restrict__ boff,
    const float* __restrict__ xl, const float* __restrict__ xr,
    const float* __restrict__ we, const float* __restrict__ att,
    const float* __restrict__ bias, float* __restrict__ partials, int N)
{
    __shared__ uint2 srec[CAP];
    __shared__ int scnt[BNODES], soff[BNODES], scur[BNODES];
    __shared__ float smr[8][2][8];
    bucket_sort_stage(grecs, boff, srec, scnt, soff, scur);
    int t = threadIdx.x;
    int nl = t >> 1, h = t & 1;
    int n = blockIdx.x * BNODES + nl;
    float out[8];
    if (n < N) {
        agg_from_lds(nl, h, srec, scnt, soff, n, xl, xr, we, att, bias, out);
    } else {
#pragma unroll
        for (int o = 0; o < 8; o++) out[o] = 0.f;
    }
    // wave reduce over same-parity lanes
#pragma unroll
    for (int off = 32; off >= 2; off >>= 1) {
#pragma unroll
        for (int o = 0; o < 8; o++) out[o] += __shfl_down(out[o], off, 64);
    }
    int wave = t >> 6, lane = t & 63;
    if (lane < 2) {
#pragma unroll
        for (int o = 0; o < 8; o++) smr[wave][lane][o] = out[o];
    }
    __syncthreads();
    if (t < 16) {
        int hh = t >> 3, oo = t & 7;
        float acc = 0.f;
#pragma unroll
        for (int wv = 0; wv < 8; wv++) acc += smr[wv][hh][oo];
        partials[(size_t)blockIdx.x*16 + hh*8 + oo] = acc;
    }
}

// transform h by layer-2 weights -> xl2, xr2
__global__ void __launch_bounds__(256) node_transform(
    const float* __restrict__ hin,
    const float* __restrict__ wl2, const float* __restrict__ bl2,
    const float* __restrict__ wr2, const float* __restrict__ br2,
    float* __restrict__ xl2, float* __restrict__ xr2, int N)
{
    int n = blockIdx.x * 256 + threadIdx.x;
    if (n >= N) return;
    float h[HO];
    const float4* hp = (const float4*)(hin + (size_t)n*HO);
#pragma unroll
    for (int q = 0; q < 4; q++) {
        float4 v = hp[q];
        h[4*q]=v.x; h[4*q+1]=v.y; h[4*q+2]=v.z; h[4*q+3]=v.w;
    }
    float ol[HO], orr[HO];
#pragma unroll
    for (int j = 0; j < HO; j++) {
        float a = bl2[j], b = br2[j];
#pragma unroll
        for (int k = 0; k < HO; k++) { a += wl2[HO*j+k]*h[k]; b += wr2[HO*j+k]*h[k]; }
        ol[j] = a; orr[j] = b;
    }
    float4* xl4 = (float4*)(xl2 + (size_t)n*HO);
    float4* xr4 = (float4*)(xr2 + (size_t)n*HO);
#pragma unroll
    for (int q = 0; q < 4; q++) {
        xl4[q] = make_float4(ol[4*q], ol[4*q+1], ol[4*q+2], ol[4*q+3]);
        xr4[q] = make_float4(orr[4*q], orr[4*q+1], orr[4*q+2], orr[4*q+3]);
    }
}

// ---------------- final tail: sum partials -> pool, MLP chain + softmax ----------------
__global__ void __launch_bounds__(64) final_mlp(
    const float* __restrict__ partials, int nparts,
    const float* __restrict__ meta,
    const float* __restrict__ sp1_w, const float* __restrict__ sp1_b,
    const float* __restrict__ sp2_w, const float* __restrict__ sp2_b,
    const float* __restrict__ me_w, const float* __restrict__ me_b,
    const float* __restrict__ fc1_w, const float* __restrict__ fc1_b,
    const float* __restrict__ fc2_w, const float* __restrict__ fc2_b,
    const float* __restrict__ fc3_w, const float* __restrict__ fc3_b,
    float* __restrict__ out)
{
    __shared__ float red[4][16];
    __shared__ float pool[16];
    __shared__ float s1[64], zb[24], z1[24], z2[8];
    int t = threadIdx.x;
    {
        int col = t & 15, r0 = t >> 4;
        float acc = 0.f;
        for (int r = r0; r < nparts; r += 4) acc += partials[(size_t)r*16 + col];
        red[r0][col] = acc;
    }
    __syncthreads();
    if (t < 16) pool[t] = red[0][t] + red[1][t] + red[2][t] + red[3][t];
    __syncthreads();
    {
        float acc = sp1_b[t];
        for (int k = 0; k < 16; k++) acc += pool[k]*sp1_w[t*16+k];
        s1[t] = lrelu(acc, 0.1f);
    }
    __syncthreads();
    if (t < 16) {
        float acc = sp2_b[t];
        for (int k = 0; k < 64; k++) acc += s1[k]*sp2_w[t*64+k];
        zb[t] = acc;
    } else if (t < 24) {
        int j = t - 16;
        float acc = me_b[j];
        for (int k = 0; k < 6; k++) acc += meta[k]*me_w[j*6+k];
        zb[t] = lrelu(acc, 0.1f);
    }
    __syncthreads();
    if (t < 24) {
        float acc = fc1_b[t];
        for (int k = 0; k < 24; k++) acc += zb[k]*fc1_w[t*24+k];
        z1[t] = lrelu(acc, 0.1f);
    }
    __syncthreads();
    if (t < 8) {
        float acc = fc2_b[t];
        for (int k = 0; k < 24; k++) acc += z1[k]*fc2_w[t*24+k];
        z2[t] = lrelu(acc, 0.1f);
    }
    __syncthreads();
    if (t == 0) {
        float z3[3]; float mxv = -1e30f;
        for (int j = 0; j < 3; j++) {
            float acc = fc3_b[j];
            for (int k = 0; k < 8; k++) acc += z2[k]*fc3_w[j*8+k];
            z3[j] = acc; mxv = fmaxf(mxv, acc);
        }
        float s = 0.f;
        for (int j = 0; j < 3; j++) { z3[j] = __expf(z3[j]-mxv); s += z3[j]; }
        for (int j = 0; j < 3; j++) out[j] = z3[j]/s;
    }
}

extern "C" void kernel_launch(void* const* d_in, const int* in_sizes, int n_in,
                              void* d_out, int out_size, void* d_ws, size_t ws_size,
                              hipStream_t stream)
{
    const float* x      = (const float*)d_in[0];
    const int*   eidx   = (const int*)  d_in[1];
    const float* eattr  = (const float*)d_in[2];
    const float* meta   = (const float*)d_in[3];
    const float* ft1_w  = (const float*)d_in[4];
    const float* ft1_b  = (const float*)d_in[5];
    const float* ft2_w  = (const float*)d_in[6];
    const float* ft2_b  = (const float*)d_in[7];
    const float* g1_wl  = (const float*)d_in[8];
    const float* g1_bl  = (const float*)d_in[9];
    const float* g1_wr  = (const float*)d_in[10];
    const float* g1_br  = (const float*)d_in[11];
    const float* g1_we  = (const float*)d_in[12];
    const float* g1_att = (const float*)d_in[13];
    const float* g1_bias= (const float*)d_in[14];
    const float* g2_wl  = (const float*)d_in[15];
    const float* g2_bl  = (const float*)d_in[16];
    const float* g2_wr  = (const float*)d_in[17];
    const float* g2_br  = (const float*)d_in[18];
    const float* g2_we  = (const float*)d_in[19];
    const float* g2_att = (const float*)d_in[20];
    const float* g2_bias= (const float*)d_in[21];
    const float* sp1_w  = (const float*)d_in[22];
    const float* sp1_b  = (const float*)d_in[23];
    const float* sp2_w  = (const float*)d_in[24];
    const float* sp2_b  = (const float*)d_in[25];
    const float* me_w   = (const float*)d_in[26];
    const float* me_b   = (const float*)d_in[27];
    const float* fc1_w  = (const float*)d_in[28];
    const float* fc1_b  = (const float*)d_in[29];
    const float* fc2_w  = (const float*)d_in[30];
    const float* fc2_b  = (const float*)d_in[31];
    const float* fc3_w  = (const float*)d_in[32];
    const float* fc3_b  = (const float*)d_in[33];
    float* out = (float*)d_out;

    const int N = in_sizes[0] / 3;
    const int E = in_sizes[2] / 2;
    const int* src = eidx;
    const int* dst = eidx + E;

    const int BN = (N + 255) / 256;
    const int BE = (E + 255) / 256;
    const int NB = (N + BNODES - 1) >> BSHIFT;   // buckets; must be <= 1024

    // workspace layout (256B-aligned):
    char* w = (char*)d_ws;
    size_t off = 0;
    auto take = [&](size_t bytes) { size_t o = off; off += (bytes + 255) & ~(size_t)255; return o; };
    int*   boff     = (int*)  (w + take((size_t)4*(NB+1)));
    int*   bcnt     = (int*)  (w + take((size_t)4*NB));
    int*   bcur     = (int*)  (w + take((size_t)4*NB));
    float* partials = (float*)(w + take((size_t)4*16*NB));
    uint2* grecs    = (uint2*)(w + take((size_t)8*E));
    float* xl       = (float*)(w + take((size_t)64*N));
    float* xr       = (float*)(w + take((size_t)64*N));
    float* hbuf     = (float*)(w + take((size_t)64*N));
    // total ~= 40MB + 48MB + ~90KB ~= 88.1 MB

    hipMemsetAsync(bcnt, 0, (size_t)4*NB, stream);

    // node features + layer-1 transforms
    node_l1<<<BN, 256, 0, stream>>>(x, ft1_w, ft1_b, ft2_w, ft2_b,
                                    g1_wl, g1_bl, g1_wr, g1_br, xl, xr, N);
    // bucket build (graph-only; shared by both layers)
    k_bhist<<<BE, 256, 0, stream>>>(dst, bcnt, E);
    k_bscan<<<1, 1024, 0, stream>>>(bcnt, boff, bcur, NB, E);
    k_bscatter<<<BE, 256, 0, stream>>>(src, dst, eattr, bcur, grecs, E);

    // ---- layer 1 ----
    agg_l1<<<NB, 512, 0, stream>>>(grecs, boff, xl, xr, g1_we, g1_att, g1_bias, hbuf, N);
    node_transform<<<BN, 256, 0, stream>>>(hbuf, g2_wl, g2_bl, g2_wr, g2_br, xl, xr, N);
    // ---- layer 2 ----
    agg_l2<<<NB, 512, 0, stream>>>(grecs, boff, xl, xr, g2_we, g2_att, g2_bias, partials, N);
    // ---- tail ----
    final_mlp<<<1, 64, 0, stream>>>(partials, NB, meta, sp1_w, sp1_b, sp2_w, sp2_b,
                                    me_w, me_b, fc1_w, fc1_b, fc2_w, fc2_b,
                                    fc3_w, fc3_b, out);
}

// Round 5
// 1053.336 us; speedup vs baseline: 2.3289x; 2.3289x over previous
//
#include <hip/hip_runtime.h>
#include <hip/hip_bf16.h>
#include <hip/hip_fp16.h>
#include <math.h>

// SportsGNN: ftMLP -> GATv2 x2 -> sumpool -> MLP -> softmax
// N=250000, E=5000000, H=2, O=8 (HO=16)
// Round-5: round-3 CSR structure (fine-grained 250k cursors - no atomic
// contention) + packed uint2 edge records (one 8B scattered store, validated
// by round-4's WRITE_SIZE drop) + 4-wide gather pipeline in agg.

#define HO 16

__device__ __forceinline__ float lrelu(float x, float s) { return x > 0.f ? x : s * x; }

// ---------------- node kernel, layer 1: x[N,3] -> ftMLP -> xl1,xr1 [N,16] ----------------
__global__ void __launch_bounds__(256) node_l1(
    const float* __restrict__ x,
    const float* __restrict__ ft1_w, const float* __restrict__ ft1_b,
    const float* __restrict__ ft2_w, const float* __restrict__ ft2_b,
    const float* __restrict__ wl, const float* __restrict__ bl,
    const float* __restrict__ wr, const float* __restrict__ br,
    float* __restrict__ xl, float* __restrict__ xr, int N)
{
    int n = blockIdx.x * 256 + threadIdx.x;
    if (n >= N) return;
    float x0 = x[3*n], x1 = x[3*n+1], x2 = x[3*n+2];
    float h1[8];
#pragma unroll
    for (int j = 0; j < 8; j++) {
        float a = ft1_w[3*j]*x0 + ft1_w[3*j+1]*x1 + ft1_w[3*j+2]*x2 + ft1_b[j];
        h1[j] = lrelu(a, 0.1f);
    }
    float h2[8];
#pragma unroll
    for (int j = 0; j < 8; j++) {
        float a = ft2_b[j];
#pragma unroll
        for (int k = 0; k < 8; k++) a += ft2_w[8*j+k]*h1[k];
        h2[j] = lrelu(a, 0.1f);
    }
    float ol[HO], orr[HO];
#pragma unroll
    for (int j = 0; j < HO; j++) {
        float a = bl[j], b = br[j];
#pragma unroll
        for (int k = 0; k < 8; k++) { a += wl[8*j+k]*h2[k]; b += wr[8*j+k]*h2[k]; }
        ol[j] = a; orr[j] = b;
    }
    float4* xl4 = (float4*)(xl + (size_t)n*HO);
    float4* xr4 = (float4*)(xr + (size_t)n*HO);
#pragma unroll
    for (int q = 0; q < 4; q++) {
        xl4[q] = make_float4(ol[4*q], ol[4*q+1], ol[4*q+2], ol[4*q+3]);
        xr4[q] = make_float4(orr[4*q], orr[4*q+1], orr[4*q+2], orr[4*q+3]);
    }
}

// ---------------- CSR build ----------------
__global__ void __launch_bounds__(256) k_hist(
    const int* __restrict__ dst, int* __restrict__ deg, int E)
{
    int e = blockIdx.x * 256 + threadIdx.x;
    if (e < E) atomicAdd(&deg[dst[e]], 1);
}

__global__ void __launch_bounds__(256) k_scanA(
    const int* __restrict__ deg, int* __restrict__ bsum, int N)
{
    __shared__ int r[256];
    int t = threadIdx.x;
    int n = blockIdx.x * 256 + t;
    r[t] = (n < N) ? deg[n] : 0;
    __syncthreads();
#pragma unroll
    for (int off = 128; off > 0; off >>= 1) {
        if (t < off) r[t] += r[t + off];
        __syncthreads();
    }
    if (t == 0) bsum[blockIdx.x] = r[0];
}

__global__ void __launch_bounds__(1024) k_scanB(int* __restrict__ bsum, int nb)
{
    __shared__ int s[1024];
    int t = threadIdx.x;
    int v = (t < nb) ? bsum[t] : 0;
    s[t] = v;
    __syncthreads();
    for (int off = 1; off < 1024; off <<= 1) {
        int add = (t >= off) ? s[t - off] : 0;
        __syncthreads();
        s[t] += add;
        __syncthreads();
    }
    if (t < nb) bsum[t] = s[t] - v;   // exclusive
}

__global__ void __launch_bounds__(256) k_scanC(
    int* deg_cursor, const int* __restrict__ bsum,
    int* __restrict__ row, int N, int E)
{
    __shared__ int s[256];
    int t = threadIdx.x;
    int n = blockIdx.x * 256 + t;
    int d = (n < N) ? deg_cursor[n] : 0;
    s[t] = d;
    __syncthreads();
    for (int off = 1; off < 256; off <<= 1) {
        int add = (t >= off) ? s[t - off] : 0;
        __syncthreads();
        s[t] += add;
        __syncthreads();
    }
    int val = bsum[blockIdx.x] + s[t] - d;   // exclusive prefix
    if (n < N) { row[n] = val; deg_cursor[n] = val; }
    if (n == 0) row[N] = E;
}

// scatter: one packed 8B record per edge, in dst-sorted position
// rec.x = src, rec.y = half2(eattr)
__global__ void __launch_bounds__(256) k_scatter(
    const int* __restrict__ src, const int* __restrict__ dst,
    const float* __restrict__ eattr, int* __restrict__ cursor,
    uint2* __restrict__ recs, int E)
{
    int e = blockIdx.x * 256 + threadIdx.x;
    if (e >= E) return;
    int pos = atomicAdd(&cursor[dst[e]], 1);
    float2 ea = ((const float2*)eattr)[e];
    __half2 hv = __floats2half2_rn(ea.x, ea.y);
    unsigned int eb = *reinterpret_cast<unsigned int*>(&hv);
    recs[pos] = make_uint2((unsigned int)src[e], eb);
}

// ---------------- per-(node,head) online-softmax aggregation ----------------
struct AggState { float m, s, acc[8]; };

__device__ __forceinline__ void agg_edge(
    AggState& st, const float* va, const float* xd,
    const float* w0, const float* w1, const float* at,
    float ea0, float ea1)
{
    float lg = 0.f;
#pragma unroll
    for (int o = 0; o < 8; o++) {
        float mv = va[o] + xd[o] + (w0[o]*ea0 + w1[o]*ea1);
        mv = mv > 0.f ? mv : 0.2f*mv;      // leaky_relu 0.2
        lg += mv * at[o];
    }
    float nm = fmaxf(st.m, lg);
    float sc = __expf(st.m - nm);
    float wv = __expf(lg - nm);
    st.s = st.s*sc + wv;
#pragma unroll
    for (int o = 0; o < 8; o++) st.acc[o] = st.acc[o]*sc + wv*va[o];
    st.m = nm;
}

__device__ __forceinline__ void agg_node_head(
    int n, int h,
    const int* __restrict__ row, const uint2* __restrict__ recs,
    const float* __restrict__ xl, const float* __restrict__ xr,
    const float* __restrict__ we, const float* __restrict__ att,
    const float* __restrict__ bias, float* out)
{
    int kb = h*8;
    float xd[8], w0[8], w1[8], at[8];
    {
        const float4* xrp = (const float4*)(xr + (size_t)n*HO + kb);
        float4 d0 = xrp[0], d1 = xrp[1];
        xd[0]=d0.x; xd[1]=d0.y; xd[2]=d0.z; xd[3]=d0.w;
        xd[4]=d1.x; xd[5]=d1.y; xd[6]=d1.z; xd[7]=d1.w;
    }
#pragma unroll
    for (int o = 0; o < 8; o++) {
        w0[o] = we[2*(kb+o)];
        w1[o] = we[2*(kb+o)+1];
        at[o] = att[kb+o];
    }
    AggState st;
    st.m = -INFINITY; st.s = 0.f;
#pragma unroll
    for (int o = 0; o < 8; o++) st.acc[o] = 0.f;

    int i = row[n], end = row[n+1];
    // 4-wide software pipeline: all four gathers issued before serial updates
    for (; i + 4 <= end; i += 4) {
        uint2 rA = recs[i], rB = recs[i+1], rC = recs[i+2], rD = recs[i+3];
        const float4* pA = (const float4*)(xl + (size_t)rA.x*HO + kb);
        const float4* pB = (const float4*)(xl + (size_t)rB.x*HO + kb);
        const float4* pC = (const float4*)(xl + (size_t)rC.x*HO + kb);
        const float4* pD = (const float4*)(xl + (size_t)rD.x*HO + kb);
        float4 a0 = pA[0], a1 = pA[1];
        float4 b0 = pB[0], b1 = pB[1];
        float4 c0 = pC[0], c1 = pC[1];
        float4 d0 = pD[0], d1 = pD[1];
        __half2 hA = *reinterpret_cast<__half2*>(&rA.y);
        __half2 hB = *reinterpret_cast<__half2*>(&rB.y);
        __half2 hC = *reinterpret_cast<__half2*>(&rC.y);
        __half2 hD = *reinterpret_cast<__half2*>(&rD.y);
        float vA[8] = {a0.x,a0.y,a0.z,a0.w,a1.x,a1.y,a1.z,a1.w};
        float vB[8] = {b0.x,b0.y,b0.z,b0.w,b1.x,b1.y,b1.z,b1.w};
        float vC[8] = {c0.x,c0.y,c0.z,c0.w,c1.x,c1.y,c1.z,c1.w};
        float vD[8] = {d0.x,d0.y,d0.z,d0.w,d1.x,d1.y,d1.z,d1.w};
        agg_edge(st, vA, xd, w0, w1, at, __low2float(hA), __high2float(hA));
        agg_edge(st, vB, xd, w0, w1, at, __low2float(hB), __high2float(hB));
        agg_edge(st, vC, xd, w0, w1, at, __low2float(hC), __high2float(hC));
        agg_edge(st, vD, xd, w0, w1, at, __low2float(hD), __high2float(hD));
    }
    for (; i < end; i++) {
        uint2 rA = recs[i];
        const float4* pA = (const float4*)(xl + (size_t)rA.x*HO + kb);
        float4 a0 = pA[0], a1 = pA[1];
        __half2 hA = *reinterpret_cast<__half2*>(&rA.y);
        float vA[8] = {a0.x,a0.y,a0.z,a0.w,a1.x,a1.y,a1.z,a1.w};
        agg_edge(st, vA, xd, w0, w1, at, __low2float(hA), __high2float(hA));
    }
    float inv = 1.f/(st.s + 1e-16f);
#pragma unroll
    for (int o = 0; o < 8; o++) out[o] = st.acc[o]*inv + bias[kb+o];
}

// layer 1: + lrelu(0.1), write h buffer
__global__ void __launch_bounds__(256) node_agg_l1(
    const int* __restrict__ row, const uint2* __restrict__ recs,
    const float* __restrict__ xl, const float* __restrict__ xr,
    const float* __restrict__ we, const float* __restrict__ att,
    const float* __restrict__ bias, float* __restrict__ hout, int N)
{
    int tid = blockIdx.x * 256 + threadIdx.x;
    int n = tid >> 1, h = tid & 1;
    if (n >= N) return;
    float out[8];
    agg_node_head(n, h, row, recs, xl, xr, we, att, bias, out);
    float4* hp = (float4*)(hout + (size_t)n*HO + h*8);
    hp[0] = make_float4(lrelu(out[0],0.1f), lrelu(out[1],0.1f), lrelu(out[2],0.1f), lrelu(out[3],0.1f));
    hp[1] = make_float4(lrelu(out[4],0.1f), lrelu(out[5],0.1f), lrelu(out[6],0.1f), lrelu(out[7],0.1f));
}

// transform h by layer-2 weights -> xl2, xr2
__global__ void __launch_bounds__(256) node_transform(
    const float* __restrict__ hin,
    const float* __restrict__ wl2, const float* __restrict__ bl2,
    const float* __restrict__ wr2, const float* __restrict__ br2,
    float* __restrict__ xl2, float* __restrict__ xr2, int N)
{
    int n = blockIdx.x * 256 + threadIdx.x;
    if (n >= N) return;
    float h[HO];
    const float4* hp = (const float4*)(hin + (size_t)n*HO);
#pragma unroll
    for (int q = 0; q < 4; q++) {
        float4 v = hp[q];
        h[4*q]=v.x; h[4*q+1]=v.y; h[4*q+2]=v.z; h[4*q+3]=v.w;
    }
    float ol[HO], orr[HO];
#pragma unroll
    for (int j = 0; j < HO; j++) {
        float a = bl2[j], b = br2[j];
#pragma unroll
        for (int k = 0; k < HO; k++) { a += wl2[HO*j+k]*h[k]; b += wr2[HO*j+k]*h[k]; }
        ol[j] = a; orr[j] = b;
    }
    float4* xl4 = (float4*)(xl2 + (size_t)n*HO);
    float4* xr4 = (float4*)(xr2 + (size_t)n*HO);
#pragma unroll
    for (int q = 0; q < 4; q++) {
        xl4[q] = make_float4(ol[4*q], ol[4*q+1], ol[4*q+2], ol[4*q+3]);
        xr4[q] = make_float4(orr[4*q], orr[4*q+1], orr[4*q+2], orr[4*q+3]);
    }
}

// layer 2: aggregate (+bias, no act), block-reduce, write per-block partials[16]
__global__ void __launch_bounds__(256) node_agg_l2(
    const int* __restrict__ row, const uint2* __restrict__ recs,
    const float* __restrict__ xl, const float* __restrict__ xr,
    const float* __restrict__ we, const float* __restrict__ att,
    const float* __restrict__ bias, float* __restrict__ partials, int N)
{
    int tid = blockIdx.x * 256 + threadIdx.x;
    int n = tid >> 1, h = tid & 1;
    float out[8];
    if (n < N) {
        agg_node_head(n, h, row, recs, xl, xr, we, att, bias, out);
    } else {
#pragma unroll
        for (int o = 0; o < 8; o++) out[o] = 0.f;
    }
    // wave reduce over same-parity lanes (heads interleave even/odd)
#pragma unroll
    for (int off = 32; off >= 2; off >>= 1) {
#pragma unroll
        for (int o = 0; o < 8; o++) out[o] += __shfl_down(out[o], off, 64);
    }
    __shared__ float sm[4][2][8];
    int wave = threadIdx.x >> 6, lane = threadIdx.x & 63;
    if (lane < 2) {
#pragma unroll
        for (int o = 0; o < 8; o++) sm[wave][lane][o] = out[o];
    }
    __syncthreads();
    if (threadIdx.x < 16) {
        int hh = threadIdx.x >> 3, oo = threadIdx.x & 7;
        float t = sm[0][hh][oo] + sm[1][hh][oo] + sm[2][hh][oo] + sm[3][hh][oo];
        partials[(size_t)blockIdx.x*16 + hh*8 + oo] = t;
    }
}

// ---------------- final tail: sum partials -> pool, then MLP chain + softmax ----------------
__global__ void __launch_bounds__(64) final_mlp(
    const float* __restrict__ partials, int nparts,
    const float* __restrict__ meta,
    const float* __restrict__ sp1_w, const float* __restrict__ sp1_b,
    const float* __restrict__ sp2_w, const float* __restrict__ sp2_b,
    const float* __restrict__ me_w, const float* __restrict__ me_b,
    const float* __restrict__ fc1_w, const float* __restrict__ fc1_b,
    const float* __restrict__ fc2_w, const float* __restrict__ fc2_b,
    const float* __restrict__ fc3_w, const float* __restrict__ fc3_b,
    float* __restrict__ out)
{
    __shared__ float red[4][16];
    __shared__ float pool[16];
    __shared__ float s1[64], zb[24], z1[24], z2[8];
    int t = threadIdx.x;
    {
        int col = t & 15, r0 = t >> 4;
        float acc = 0.f;
        for (int r = r0; r < nparts; r += 4) acc += partials[(size_t)r*16 + col];
        red[r0][col] = acc;
    }
    __syncthreads();
    if (t < 16) pool[t] = red[0][t] + red[1][t] + red[2][t] + red[3][t];
    __syncthreads();
    {
        float acc = sp1_b[t];
        for (int k = 0; k < 16; k++) acc += pool[k]*sp1_w[t*16+k];
        s1[t] = lrelu(acc, 0.1f);
    }
    __syncthreads();
    if (t < 16) {
        float acc = sp2_b[t];
        for (int k = 0; k < 64; k++) acc += s1[k]*sp2_w[t*64+k];
        zb[t] = acc;
    } else if (t < 24) {
        int j = t - 16;
        float acc = me_b[j];
        for (int k = 0; k < 6; k++) acc += meta[k]*me_w[j*6+k];
        zb[t] = lrelu(acc, 0.1f);
    }
    __syncthreads();
    if (t < 24) {
        float acc = fc1_b[t];
        for (int k = 0; k < 24; k++) acc += zb[k]*fc1_w[t*24+k];
        z1[t] = lrelu(acc, 0.1f);
    }
    __syncthreads();
    if (t < 8) {
        float acc = fc2_b[t];
        for (int k = 0; k < 24; k++) acc += z1[k]*fc2_w[t*24+k];
        z2[t] = lrelu(acc, 0.1f);
    }
    __syncthreads();
    if (t == 0) {
        float z3[3]; float mxv = -1e30f;
        for (int j = 0; j < 3; j++) {
            float acc = fc3_b[j];
            for (int k = 0; k < 8; k++) acc += z2[k]*fc3_w[j*8+k];
            z3[j] = acc; mxv = fmaxf(mxv, acc);
        }
        float s = 0.f;
        for (int j = 0; j < 3; j++) { z3[j] = __expf(z3[j]-mxv); s += z3[j]; }
        for (int j = 0; j < 3; j++) out[j] = z3[j]/s;
    }
}

extern "C" void kernel_launch(void* const* d_in, const int* in_sizes, int n_in,
                              void* d_out, int out_size, void* d_ws, size_t ws_size,
                              hipStream_t stream)
{
    const float* x      = (const float*)d_in[0];
    const int*   eidx   = (const int*)  d_in[1];
    const float* eattr  = (const float*)d_in[2];
    const float* meta   = (const float*)d_in[3];
    const float* ft1_w  = (const float*)d_in[4];
    const float* ft1_b  = (const float*)d_in[5];
    const float* ft2_w  = (const float*)d_in[6];
    const float* ft2_b  = (const float*)d_in[7];
    const float* g1_wl  = (const float*)d_in[8];
    const float* g1_bl  = (const float*)d_in[9];
    const float* g1_wr  = (const float*)d_in[10];
    const float* g1_br  = (const float*)d_in[11];
    const float* g1_we  = (const float*)d_in[12];
    const float* g1_att = (const float*)d_in[13];
    const float* g1_bias= (const float*)d_in[14];
    const float* g2_wl  = (const float*)d_in[15];
    const float* g2_bl  = (const float*)d_in[16];
    const float* g2_wr  = (const float*)d_in[17];
    const float* g2_br  = (const float*)d_in[18];
    const float* g2_we  = (const float*)d_in[19];
    const float* g2_att = (const float*)d_in[20];
    const float* g2_bias= (const float*)d_in[21];
    const float* sp1_w  = (const float*)d_in[22];
    const float* sp1_b  = (const float*)d_in[23];
    const float* sp2_w  = (const float*)d_in[24];
    const float* sp2_b  = (const float*)d_in[25];
    const float* me_w   = (const float*)d_in[26];
    const float* me_b   = (const float*)d_in[27];
    const float* fc1_w  = (const float*)d_in[28];
    const float* fc1_b  = (const float*)d_in[29];
    const float* fc2_w  = (const float*)d_in[30];
    const float* fc2_b  = (const float*)d_in[31];
    const float* fc3_w  = (const float*)d_in[32];
    const float* fc3_b  = (const float*)d_in[33];
    float* out = (float*)d_out;

    const int N = in_sizes[0] / 3;
    const int E = in_sizes[2] / 2;
    const int* src = eidx;
    const int* dst = eidx + E;

    const int BN  = (N + 255) / 256;
    const int BE  = (E + 255) / 256;
    const int BN2 = (2*N + 255) / 256;   // agg kernels: 2 threads/node
    const int nb  = BN;                  // must be <= 1024 (N <= 262144)

    // workspace layout (256B-aligned):
    char* w = (char*)d_ws;
    size_t off = 0;
    auto take = [&](size_t bytes) { size_t o = off; off += (bytes + 255) & ~(size_t)255; return o; };
    int*   row      = (int*)  (w + take((size_t)4*(N+1)));
    int*   cursor   = (int*)  (w + take((size_t)4*N));
    int*   bsum     = (int*)  (w + take(4096));
    float* partials = (float*)(w + take((size_t)4*16*BN2));
    uint2* recs     = (uint2*)(w + take((size_t)8*E));
    float* xl       = (float*)(w + take((size_t)64*N));
    float* xr       = (float*)(w + take((size_t)64*N));
    float* hbuf     = (float*)(w + take((size_t)64*N));
    // total ~= 2MB + 125KB + 40MB + 48MB ~= 90MB

    hipMemsetAsync(cursor, 0, (size_t)4*N, stream);

    // node features + layer-1 transforms
    node_l1<<<BN, 256, 0, stream>>>(x, ft1_w, ft1_b, ft2_w, ft2_b,
                                    g1_wl, g1_bl, g1_wr, g1_br, xl, xr, N);
    // CSR build + packed permuted edge records (graph-only; shared by both layers)
    k_hist<<<BE, 256, 0, stream>>>(dst, cursor, E);
    k_scanA<<<nb, 256, 0, stream>>>(cursor, bsum, N);
    k_scanB<<<1, 1024, 0, stream>>>(bsum, nb);
    k_scanC<<<nb, 256, 0, stream>>>(cursor, bsum, row, N, E);
    k_scatter<<<BE, 256, 0, stream>>>(src, dst, eattr, cursor, recs, E);

    // ---- layer 1 ----
    node_agg_l1<<<BN2, 256, 0, stream>>>(row, recs, xl, xr,
                                         g1_we, g1_att, g1_bias, hbuf, N);
    node_transform<<<BN, 256, 0, stream>>>(hbuf, g2_wl, g2_bl, g2_wr, g2_br, xl, xr, N);
    // ---- layer 2 ----
    node_agg_l2<<<BN2, 256, 0, stream>>>(row, recs, xl, xr,
                                         g2_we, g2_att, g2_bias, partials, N);
    // ---- tail ----
    final_mlp<<<1, 64, 0, stream>>>(partials, BN2, meta, sp1_w, sp1_b, sp2_w, sp2_b,
                                    me_w, me_b, fc1_w, fc1_b, fc2_w, fc2_b,
                                    fc3_w, fc3_b, out);
}

// Round 6
// 978.484 us; speedup vs baseline: 2.5071x; 1.0765x over previous
//
#include <hip/hip_runtime.h>
#include <hip/hip_bf16.h>
#include <hip/hip_fp16.h>
#include <math.h>

// SportsGNN: ftMLP -> GATv2 x2 -> sumpool -> MLP -> softmax
// N=250000, E=5000000, H=2, O=8 (HO=16)
// Round-6: round-5 skeleton + fp16 xl node table (8 MB instead of 16 MB)
// to halve random-gather line traffic in the agg kernels (the dominant cost).

#define HO 16

__device__ __forceinline__ float lrelu(float x, float s) { return x > 0.f ? x : s * x; }

// pack 8 floats -> 16B of fp16 at p (16B aligned)
__device__ __forceinline__ void store_half8(__half* p, const float* v) {
    __half2 hx[4];
#pragma unroll
    for (int q = 0; q < 4; q++) hx[q] = __floats2half2_rn(v[2*q], v[2*q+1]);
    *reinterpret_cast<uint4*>(p) = *reinterpret_cast<uint4*>(hx);
}

// load 16B of fp16 -> 8 floats
__device__ __forceinline__ void load_half8(const __half* p, float* v) {
    uint4 u = *reinterpret_cast<const uint4*>(p);
    const __half2* h2 = reinterpret_cast<const __half2*>(&u);
#pragma unroll
    for (int q = 0; q < 4; q++) {
        float2 f = __half22float2(h2[q]);
        v[2*q] = f.x; v[2*q+1] = f.y;
    }
}

// ---------------- node kernel, layer 1: x[N,3] -> ftMLP -> xl1(fp16),xr1(fp32) ----------------
__global__ void __launch_bounds__(256) node_l1(
    const float* __restrict__ x,
    const float* __restrict__ ft1_w, const float* __restrict__ ft1_b,
    const float* __restrict__ ft2_w, const float* __restrict__ ft2_b,
    const float* __restrict__ wl, const float* __restrict__ bl,
    const float* __restrict__ wr, const float* __restrict__ br,
    __half* __restrict__ xl, float* __restrict__ xr, int N)
{
    int n = blockIdx.x * 256 + threadIdx.x;
    if (n >= N) return;
    float x0 = x[3*n], x1 = x[3*n+1], x2 = x[3*n+2];
    float h1[8];
#pragma unroll
    for (int j = 0; j < 8; j++) {
        float a = ft1_w[3*j]*x0 + ft1_w[3*j+1]*x1 + ft1_w[3*j+2]*x2 + ft1_b[j];
        h1[j] = lrelu(a, 0.1f);
    }
    float h2[8];
#pragma unroll
    for (int j = 0; j < 8; j++) {
        float a = ft2_b[j];
#pragma unroll
        for (int k = 0; k < 8; k++) a += ft2_w[8*j+k]*h1[k];
        h2[j] = lrelu(a, 0.1f);
    }
    float ol[HO], orr[HO];
#pragma unroll
    for (int j = 0; j < HO; j++) {
        float a = bl[j], b = br[j];
#pragma unroll
        for (int k = 0; k < 8; k++) { a += wl[8*j+k]*h2[k]; b += wr[8*j+k]*h2[k]; }
        ol[j] = a; orr[j] = b;
    }
    store_half8(xl + (size_t)n*HO,     ol);
    store_half8(xl + (size_t)n*HO + 8, ol + 8);
    float4* xr4 = (float4*)(xr + (size_t)n*HO);
#pragma unroll
    for (int q = 0; q < 4; q++)
        xr4[q] = make_float4(orr[4*q], orr[4*q+1], orr[4*q+2], orr[4*q+3]);
}

// ---------------- CSR build ----------------
__global__ void __launch_bounds__(256) k_hist(
    const int* __restrict__ dst, int* __restrict__ deg, int E)
{
    int e = blockIdx.x * 256 + threadIdx.x;
    if (e < E) atomicAdd(&deg[dst[e]], 1);
}

__global__ void __launch_bounds__(256) k_scanA(
    const int* __restrict__ deg, int* __restrict__ bsum, int N)
{
    __shared__ int r[256];
    int t = threadIdx.x;
    int n = blockIdx.x * 256 + t;
    r[t] = (n < N) ? deg[n] : 0;
    __syncthreads();
#pragma unroll
    for (int off = 128; off > 0; off >>= 1) {
        if (t < off) r[t] += r[t + off];
        __syncthreads();
    }
    if (t == 0) bsum[blockIdx.x] = r[0];
}

__global__ void __launch_bounds__(1024) k_scanB(int* __restrict__ bsum, int nb)
{
    __shared__ int s[1024];
    int t = threadIdx.x;
    int v = (t < nb) ? bsum[t] : 0;
    s[t] = v;
    __syncthreads();
    for (int off = 1; off < 1024; off <<= 1) {
        int add = (t >= off) ? s[t - off] : 0;
        __syncthreads();
        s[t] += add;
        __syncthreads();
    }
    if (t < nb) bsum[t] = s[t] - v;   // exclusive
}

__global__ void __launch_bounds__(256) k_scanC(
    int* deg_cursor, const int* __restrict__ bsum,
    int* __restrict__ row, int N, int E)
{
    __shared__ int s[256];
    int t = threadIdx.x;
    int n = blockIdx.x * 256 + t;
    int d = (n < N) ? deg_cursor[n] : 0;
    s[t] = d;
    __syncthreads();
    for (int off = 1; off < 256; off <<= 1) {
        int add = (t >= off) ? s[t - off] : 0;
        __syncthreads();
        s[t] += add;
        __syncthreads();
    }
    int val = bsum[blockIdx.x] + s[t] - d;   // exclusive prefix
    if (n < N) { row[n] = val; deg_cursor[n] = val; }
    if (n == 0) row[N] = E;
}

// scatter: one packed 8B record per edge, in dst-sorted position
// rec.x = src, rec.y = half2(eattr)
__global__ void __launch_bounds__(256) k_scatter(
    const int* __restrict__ src, const int* __restrict__ dst,
    const float* __restrict__ eattr, int* __restrict__ cursor,
    uint2* __restrict__ recs, int E)
{
    int e = blockIdx.x * 256 + threadIdx.x;
    if (e >= E) return;
    int pos = atomicAdd(&cursor[dst[e]], 1);
    float2 ea = ((const float2*)eattr)[e];
    __half2 hv = __floats2half2_rn(ea.x, ea.y);
    unsigned int eb = *reinterpret_cast<unsigned int*>(&hv);
    recs[pos] = make_uint2((unsigned int)src[e], eb);
}

// ---------------- per-(node,head) online-softmax aggregation ----------------
struct AggState { float m, s, acc[8]; };

__device__ __forceinline__ void agg_edge(
    AggState& st, const float* va, const float* xd,
    const float* w0, const float* w1, const float* at,
    float ea0, float ea1)
{
    float lg = 0.f;
#pragma unroll
    for (int o = 0; o < 8; o++) {
        float mv = va[o] + xd[o] + (w0[o]*ea0 + w1[o]*ea1);
        mv = mv > 0.f ? mv : 0.2f*mv;      // leaky_relu 0.2
        lg += mv * at[o];
    }
    float nm = fmaxf(st.m, lg);
    float sc = __expf(st.m - nm);
    float wv = __expf(lg - nm);
    st.s = st.s*sc + wv;
#pragma unroll
    for (int o = 0; o < 8; o++) st.acc[o] = st.acc[o]*sc + wv*va[o];
    st.m = nm;
}

__device__ __forceinline__ void agg_node_head(
    int n, int h,
    const int* __restrict__ row, const uint2* __restrict__ recs,
    const __half* __restrict__ xl, const float* __restrict__ xr,
    const float* __restrict__ we, const float* __restrict__ att,
    const float* __restrict__ bias, float* out)
{
    int kb = h*8;
    float xd[8], w0[8], w1[8], at[8];
    {
        const float4* xrp = (const float4*)(xr + (size_t)n*HO + kb);
        float4 d0 = xrp[0], d1 = xrp[1];
        xd[0]=d0.x; xd[1]=d0.y; xd[2]=d0.z; xd[3]=d0.w;
        xd[4]=d1.x; xd[5]=d1.y; xd[6]=d1.z; xd[7]=d1.w;
    }
#pragma unroll
    for (int o = 0; o < 8; o++) {
        w0[o] = we[2*(kb+o)];
        w1[o] = we[2*(kb+o)+1];
        at[o] = att[kb+o];
    }
    AggState st;
    st.m = -INFINITY; st.s = 0.f;
#pragma unroll
    for (int o = 0; o < 8; o++) st.acc[o] = 0.f;

    int i = row[n], end = row[n+1];
    // 4-wide software pipeline: all four 16B fp16 gathers issued before updates
    for (; i + 4 <= end; i += 4) {
        uint2 rA = recs[i], rB = recs[i+1], rC = recs[i+2], rD = recs[i+3];
        float vA[8], vB[8], vC[8], vD[8];
        load_half8(xl + (size_t)rA.x*HO + kb, vA);
        load_half8(xl + (size_t)rB.x*HO + kb, vB);
        load_half8(xl + (size_t)rC.x*HO + kb, vC);
        load_half8(xl + (size_t)rD.x*HO + kb, vD);
        __half2 hA = *reinterpret_cast<__half2*>(&rA.y);
        __half2 hB = *reinterpret_cast<__half2*>(&rB.y);
        __half2 hC = *reinterpret_cast<__half2*>(&rC.y);
        __half2 hD = *reinterpret_cast<__half2*>(&rD.y);
        agg_edge(st, vA, xd, w0, w1, at, __low2float(hA), __high2float(hA));
        agg_edge(st, vB, xd, w0, w1, at, __low2float(hB), __high2float(hB));
        agg_edge(st, vC, xd, w0, w1, at, __low2float(hC), __high2float(hC));
        agg_edge(st, vD, xd, w0, w1, at, __low2float(hD), __high2float(hD));
    }
    for (; i < end; i++) {
        uint2 rA = recs[i];
        float vA[8];
        load_half8(xl + (size_t)rA.x*HO + kb, vA);
        __half2 hA = *reinterpret_cast<__half2*>(&rA.y);
        agg_edge(st, vA, xd, w0, w1, at, __low2float(hA), __high2float(hA));
    }
    float inv = 1.f/(st.s + 1e-16f);
#pragma unroll
    for (int o = 0; o < 8; o++) out[o] = st.acc[o]*inv + bias[kb+o];
}

// layer 1: + lrelu(0.1), write h buffer
__global__ void __launch_bounds__(256) node_agg_l1(
    const int* __restrict__ row, const uint2* __restrict__ recs,
    const __half* __restrict__ xl, const float* __restrict__ xr,
    const float* __restrict__ we, const float* __restrict__ att,
    const float* __restrict__ bias, float* __restrict__ hout, int N)
{
    int tid = blockIdx.x * 256 + threadIdx.x;
    int n = tid >> 1, h = tid & 1;
    if (n >= N) return;
    float out[8];
    agg_node_head(n, h, row, recs, xl, xr, we, att, bias, out);
    float4* hp = (float4*)(hout + (size_t)n*HO + h*8);
    hp[0] = make_float4(lrelu(out[0],0.1f), lrelu(out[1],0.1f), lrelu(out[2],0.1f), lrelu(out[3],0.1f));
    hp[1] = make_float4(lrelu(out[4],0.1f), lrelu(out[5],0.1f), lrelu(out[6],0.1f), lrelu(out[7],0.1f));
}

// transform h by layer-2 weights -> xl2(fp16), xr2(fp32)
__global__ void __launch_bounds__(256) node_transform(
    const float* __restrict__ hin,
    const float* __restrict__ wl2, const float* __restrict__ bl2,
    const float* __restrict__ wr2, const float* __restrict__ br2,
    __half* __restrict__ xl2, float* __restrict__ xr2, int N)
{
    int n = blockIdx.x * 256 + threadIdx.x;
    if (n >= N) return;
    float h[HO];
    const float4* hp = (const float4*)(hin + (size_t)n*HO);
#pragma unroll
    for (int q = 0; q < 4; q++) {
        float4 v = hp[q];
        h[4*q]=v.x; h[4*q+1]=v.y; h[4*q+2]=v.z; h[4*q+3]=v.w;
    }
    float ol[HO], orr[HO];
#pragma unroll
    for (int j = 0; j < HO; j++) {
        float a = bl2[j], b = br2[j];
#pragma unroll
        for (int k = 0; k < HO; k++) { a += wl2[HO*j+k]*h[k]; b += wr2[HO*j+k]*h[k]; }
        ol[j] = a; orr[j] = b;
    }
    store_half8(xl2 + (size_t)n*HO,     ol);
    store_half8(xl2 + (size_t)n*HO + 8, ol + 8);
    float4* xr4 = (float4*)(xr2 + (size_t)n*HO);
#pragma unroll
    for (int q = 0; q < 4; q++)
        xr4[q] = make_float4(orr[4*q], orr[4*q+1], orr[4*q+2], orr[4*q+3]);
}

// layer 2: aggregate (+bias, no act), block-reduce, write per-block partials[16]
__global__ void __launch_bounds__(256) node_agg_l2(
    const int* __restrict__ row, const uint2* __restrict__ recs,
    const __half* __restrict__ xl, const float* __restrict__ xr,
    const float* __restrict__ we, const float* __restrict__ att,
    const float* __restrict__ bias, float* __restrict__ partials, int N)
{
    int tid = blockIdx.x * 256 + threadIdx.x;
    int n = tid >> 1, h = tid & 1;
    float out[8];
    if (n < N) {
        agg_node_head(n, h, row, recs, xl, xr, we, att, bias, out);
    } else {
#pragma unroll
        for (int o = 0; o < 8; o++) out[o] = 0.f;
    }
    // wave reduce over same-parity lanes (heads interleave even/odd)
#pragma unroll
    for (int off = 32; off >= 2; off >>= 1) {
#pragma unroll
        for (int o = 0; o < 8; o++) out[o] += __shfl_down(out[o], off, 64);
    }
    __shared__ float sm[4][2][8];
    int wave = threadIdx.x >> 6, lane = threadIdx.x & 63;
    if (lane < 2) {
#pragma unroll
        for (int o = 0; o < 8; o++) sm[wave][lane][o] = out[o];
    }
    __syncthreads();
    if (threadIdx.x < 16) {
        int hh = threadIdx.x >> 3, oo = threadIdx.x & 7;
        float t = sm[0][hh][oo] + sm[1][hh][oo] + sm[2][hh][oo] + sm[3][hh][oo];
        partials[(size_t)blockIdx.x*16 + hh*8 + oo] = t;
    }
}

// ---------------- final tail: sum partials -> pool, then MLP chain + softmax ----------------
__global__ void __launch_bounds__(64) final_mlp(
    const float* __restrict__ partials, int nparts,
    const float* __restrict__ meta,
    const float* __restrict__ sp1_w, const float* __restrict__ sp1_b,
    const float* __restrict__ sp2_w, const float* __restrict__ sp2_b,
    const float* __restrict__ me_w, const float* __restrict__ me_b,
    const float* __restrict__ fc1_w, const float* __restrict__ fc1_b,
    const float* __restrict__ fc2_w, const float* __restrict__ fc2_b,
    const float* __restrict__ fc3_w, const float* __restrict__ fc3_b,
    float* __restrict__ out)
{
    __shared__ float red[4][16];
    __shared__ float pool[16];
    __shared__ float s1[64], zb[24], z1[24], z2[8];
    int t = threadIdx.x;
    {
        int col = t & 15, r0 = t >> 4;
        float acc = 0.f;
        for (int r = r0; r < nparts; r += 4) acc += partials[(size_t)r*16 + col];
        red[r0][col] = acc;
    }
    __syncthreads();
    if (t < 16) pool[t] = red[0][t] + red[1][t] + red[2][t] + red[3][t];
    __syncthreads();
    {
        float acc = sp1_b[t];
        for (int k = 0; k < 16; k++) acc += pool[k]*sp1_w[t*16+k];
        s1[t] = lrelu(acc, 0.1f);
    }
    __syncthreads();
    if (t < 16) {
        float acc = sp2_b[t];
        for (int k = 0; k < 64; k++) acc += s1[k]*sp2_w[t*64+k];
        zb[t] = acc;
    } else if (t < 24) {
        int j = t - 16;
        float acc = me_b[j];
        for (int k = 0; k < 6; k++) acc += meta[k]*me_w[j*6+k];
        zb[t] = lrelu(acc, 0.1f);
    }
    __syncthreads();
    if (t < 24) {
        float acc = fc1_b[t];
        for (int k = 0; k < 24; k++) acc += zb[k]*fc1_w[t*24+k];
        z1[t] = lrelu(acc, 0.1f);
    }
    __syncthreads();
    if (t < 8) {
        float acc = fc2_b[t];
        for (int k = 0; k < 24; k++) acc += z1[k]*fc2_w[t*24+k];
        z2[t] = lrelu(acc, 0.1f);
    }
    __syncthreads();
    if (t == 0) {
        float z3[3]; float mxv = -1e30f;
        for (int j = 0; j < 3; j++) {
            float acc = fc3_b[j];
            for (int k = 0; k < 8; k++) acc += z2[k]*fc3_w[j*8+k];
            z3[j] = acc; mxv = fmaxf(mxv, acc);
        }
        float s = 0.f;
        for (int j = 0; j < 3; j++) { z3[j] = __expf(z3[j]-mxv); s += z3[j]; }
        for (int j = 0; j < 3; j++) out[j] = z3[j]/s;
    }
}

extern "C" void kernel_launch(void* const* d_in, const int* in_sizes, int n_in,
                              void* d_out, int out_size, void* d_ws, size_t ws_size,
                              hipStream_t stream)
{
    const float* x      = (const float*)d_in[0];
    const int*   eidx   = (const int*)  d_in[1];
    const float* eattr  = (const float*)d_in[2];
    const float* meta   = (const float*)d_in[3];
    const float* ft1_w  = (const float*)d_in[4];
    const float* ft1_b  = (const float*)d_in[5];
    const float* ft2_w  = (const float*)d_in[6];
    const float* ft2_b  = (const float*)d_in[7];
    const float* g1_wl  = (const float*)d_in[8];
    const float* g1_bl  = (const float*)d_in[9];
    const float* g1_wr  = (const float*)d_in[10];
    const float* g1_br  = (const float*)d_in[11];
    const float* g1_we  = (const float*)d_in[12];
    const float* g1_att = (const float*)d_in[13];
    const float* g1_bias= (const float*)d_in[14];
    const float* g2_wl  = (const float*)d_in[15];
    const float* g2_bl  = (const float*)d_in[16];
    const float* g2_wr  = (const float*)d_in[17];
    const float* g2_br  = (const float*)d_in[18];
    const float* g2_we  = (const float*)d_in[19];
    const float* g2_att = (const float*)d_in[20];
    const float* g2_bias= (const float*)d_in[21];
    const float* sp1_w  = (const float*)d_in[22];
    const float* sp1_b  = (const float*)d_in[23];
    const float* sp2_w  = (const float*)d_in[24];
    const float* sp2_b  = (const float*)d_in[25];
    const float* me_w   = (const float*)d_in[26];
    const float* me_b   = (const float*)d_in[27];
    const float* fc1_w  = (const float*)d_in[28];
    const float* fc1_b  = (const float*)d_in[29];
    const float* fc2_w  = (const float*)d_in[30];
    const float* fc2_b  = (const float*)d_in[31];
    const float* fc3_w  = (const float*)d_in[32];
    const float* fc3_b  = (const float*)d_in[33];
    float* out = (float*)d_out;

    const int N = in_sizes[0] / 3;
    const int E = in_sizes[2] / 2;
    const int* src = eidx;
    const int* dst = eidx + E;

    const int BN  = (N + 255) / 256;
    const int BE  = (E + 255) / 256;
    const int BN2 = (2*N + 255) / 256;   // agg kernels: 2 threads/node
    const int nb  = BN;                  // must be <= 1024 (N <= 262144)

    // workspace layout (256B-aligned):
    char* w = (char*)d_ws;
    size_t off = 0;
    auto take = [&](size_t bytes) { size_t o = off; off += (bytes + 255) & ~(size_t)255; return o; };
    int*    row      = (int*)   (w + take((size_t)4*(N+1)));
    int*    cursor   = (int*)   (w + take((size_t)4*N));
    int*    bsum     = (int*)   (w + take(4096));
    float*  partials = (float*) (w + take((size_t)4*16*BN2));
    uint2*  recs     = (uint2*) (w + take((size_t)8*E));
    __half* xl       = (__half*)(w + take((size_t)32*N));   // fp16 node table
    float*  xr       = (float*) (w + take((size_t)64*N));
    float*  hbuf     = (float*) (w + take((size_t)64*N));
    // total ~= 2MB + 125KB + 40MB + 8MB + 32MB ~= 82MB

    hipMemsetAsync(cursor, 0, (size_t)4*N, stream);

    // node features + layer-1 transforms
    node_l1<<<BN, 256, 0, stream>>>(x, ft1_w, ft1_b, ft2_w, ft2_b,
                                    g1_wl, g1_bl, g1_wr, g1_br, xl, xr, N);
    // CSR build + packed permuted edge records (graph-only; shared by both layers)
    k_hist<<<BE, 256, 0, stream>>>(dst, cursor, E);
    k_scanA<<<nb, 256, 0, stream>>>(cursor, bsum, N);
    k_scanB<<<1, 1024, 0, stream>>>(bsum, nb);
    k_scanC<<<nb, 256, 0, stream>>>(cursor, bsum, row, N, E);
    k_scatter<<<BE, 256, 0, stream>>>(src, dst, eattr, cursor, recs, E);

    // ---- layer 1 ----
    node_agg_l1<<<BN2, 256, 0, stream>>>(row, recs, xl, xr,
                                         g1_we, g1_att, g1_bias, hbuf, N);
    node_transform<<<BN, 256, 0, stream>>>(hbuf, g2_wl, g2_bl, g2_wr, g2_br, xl, xr, N);
    // ---- layer 2 ----
    node_agg_l2<<<BN2, 256, 0, stream>>>(row, recs, xl, xr,
                                         g2_we, g2_att, g2_bias, partials, N);
    // ---- tail ----
    final_mlp<<<1, 64, 0, stream>>>(partials, BN2, meta, sp1_w, sp1_b, sp2_w, sp2_b,
                                    me_w, me_b, fc1_w, fc1_b, fc2_w, fc2_b,
                                    fc3_w, fc3_b, out);
}

// Round 7
// 792.224 us; speedup vs baseline: 3.0966x; 1.2351x over previous
//
#include <hip/hip_runtime.h>
#include <hip/hip_bf16.h>
#include <hip/hip_fp16.h>
#include <math.h>

// SportsGNN: ftMLP -> GATv2 x2 -> sumpool -> MLP -> softmax
// N=250000, E=5000000, H=2, O=8 (HO=16)
// Round-7: round-6 skeleton (fp16 xl table, 4-wide gather agg) with the
// single random-write k_scatter replaced by a two-phase partition:
//   k_part: LDS multisplit into 977 buckets (256 dst nodes each), block-level
//           range claims (1 atomic per block-bucket), semi-coalesced writes.
//   k_fine: per-bucket in-LDS bin sort by node, in-place, coalesced writeback.
// Final recs layout identical to round 6; agg kernels unchanged.

#define HO 16
#define BSHIFT 8
#define BNODES 256
#define PT 512          // k_part threads
#define PCHUNK 8192     // edges per k_part block
#define FCAP 6144       // k_fine LDS record capacity (mean ~5117, sigma ~72)

__device__ __forceinline__ float lrelu(float x, float s) { return x > 0.f ? x : s * x; }

// pack 8 floats -> 16B of fp16 at p (16B aligned)
__device__ __forceinline__ void store_half8(__half* p, const float* v) {
    __half2 hx[4];
#pragma unroll
    for (int q = 0; q < 4; q++) hx[q] = __floats2half2_rn(v[2*q], v[2*q+1]);
    *reinterpret_cast<uint4*>(p) = *reinterpret_cast<uint4*>(hx);
}

// load 16B of fp16 -> 8 floats
__device__ __forceinline__ void load_half8(const __half* p, float* v) {
    uint4 u = *reinterpret_cast<const uint4*>(p);
    const __half2* h2 = reinterpret_cast<const __half2*>(&u);
#pragma unroll
    for (int q = 0; q < 4; q++) {
        float2 f = __half22float2(h2[q]);
        v[2*q] = f.x; v[2*q+1] = f.y;
    }
}

// ---------------- node kernel, layer 1: x[N,3] -> ftMLP -> xl1(fp16),xr1(fp32) ----------------
__global__ void __launch_bounds__(256) node_l1(
    const float* __restrict__ x,
    const float* __restrict__ ft1_w, const float* __restrict__ ft1_b,
    const float* __restrict__ ft2_w, const float* __restrict__ ft2_b,
    const float* __restrict__ wl, const float* __restrict__ bl,
    const float* __restrict__ wr, const float* __restrict__ br,
    __half* __restrict__ xl, float* __restrict__ xr, int N)
{
    int n = blockIdx.x * 256 + threadIdx.x;
    if (n >= N) return;
    float x0 = x[3*n], x1 = x[3*n+1], x2 = x[3*n+2];
    float h1[8];
#pragma unroll
    for (int j = 0; j < 8; j++) {
        float a = ft1_w[3*j]*x0 + ft1_w[3*j+1]*x1 + ft1_w[3*j+2]*x2 + ft1_b[j];
        h1[j] = lrelu(a, 0.1f);
    }
    float h2[8];
#pragma unroll
    for (int j = 0; j < 8; j++) {
        float a = ft2_b[j];
#pragma unroll
        for (int k = 0; k < 8; k++) a += ft2_w[8*j+k]*h1[k];
        h2[j] = lrelu(a, 0.1f);
    }
    float ol[HO], orr[HO];
#pragma unroll
    for (int j = 0; j < HO; j++) {
        float a = bl[j], b = br[j];
#pragma unroll
        for (int k = 0; k < 8; k++) { a += wl[8*j+k]*h2[k]; b += wr[8*j+k]*h2[k]; }
        ol[j] = a; orr[j] = b;
    }
    store_half8(xl + (size_t)n*HO,     ol);
    store_half8(xl + (size_t)n*HO + 8, ol + 8);
    float4* xr4 = (float4*)(xr + (size_t)n*HO);
#pragma unroll
    for (int q = 0; q < 4; q++)
        xr4[q] = make_float4(orr[4*q], orr[4*q+1], orr[4*q+2], orr[4*q+3]);
}

// ---------------- CSR row build ----------------
__global__ void __launch_bounds__(256) k_hist(
    const int* __restrict__ dst, int* __restrict__ deg, int E)
{
    int e = blockIdx.x * 256 + threadIdx.x;
    if (e < E) atomicAdd(&deg[dst[e]], 1);
}

__global__ void __launch_bounds__(256) k_scanA(
    const int* __restrict__ deg, int* __restrict__ bsum, int N)
{
    __shared__ int r[256];
    int t = threadIdx.x;
    int n = blockIdx.x * 256 + t;
    r[t] = (n < N) ? deg[n] : 0;
    __syncthreads();
#pragma unroll
    for (int off = 128; off > 0; off >>= 1) {
        if (t < off) r[t] += r[t + off];
        __syncthreads();
    }
    if (t == 0) bsum[blockIdx.x] = r[0];
}

__global__ void __launch_bounds__(1024) k_scanB(int* __restrict__ bsum, int nb)
{
    __shared__ int s[1024];
    int t = threadIdx.x;
    int v = (t < nb) ? bsum[t] : 0;
    s[t] = v;
    __syncthreads();
    for (int off = 1; off < 1024; off <<= 1) {
        int add = (t >= off) ? s[t - off] : 0;
        __syncthreads();
        s[t] += add;
        __syncthreads();
    }
    if (t < nb) bsum[t] = s[t] - v;   // exclusive
}

__global__ void __launch_bounds__(256) k_scanC(
    const int* __restrict__ deg, const int* __restrict__ bsum,
    int* __restrict__ row, int N, int E)
{
    __shared__ int s[256];
    int t = threadIdx.x;
    int n = blockIdx.x * 256 + t;
    int d = (n < N) ? deg[n] : 0;
    s[t] = d;
    __syncthreads();
    for (int off = 1; off < 256; off <<= 1) {
        int add = (t >= off) ? s[t - off] : 0;
        __syncthreads();
        s[t] += add;
        __syncthreads();
    }
    int val = bsum[blockIdx.x] + s[t] - d;   // exclusive prefix
    if (n < N) row[n] = val;
    if (n == 0) row[N] = E;
}

// bucket write cursors: bcur[b] = row[b<<BSHIFT]
__global__ void __launch_bounds__(256) k_binit(
    const int* __restrict__ row, int* __restrict__ bcur, int NBUCK, int N)
{
    int b = blockIdx.x * 256 + threadIdx.x;
    if (b < NBUCK) {
        int n0 = b << BSHIFT;
        bcur[b] = row[n0 > N ? N : n0];
    }
}

// ---------------- phase 1: LDS multisplit into buckets ----------------
// out rec: .x = (src<<8)|(dst&255), .y = half2(eattr)
__global__ void __launch_bounds__(PT) k_part(
    const int* __restrict__ src, const int* __restrict__ dst,
    const float* __restrict__ eattr, int* __restrict__ bcur,
    uint2* __restrict__ grecs, int E)
{
    __shared__ int hist[1024], lofs[1024], gbase[1024], lcur[1024];
    __shared__ int scan_s[PT];
    __shared__ uint2 srecs[PCHUNK];
    __shared__ unsigned int gaddr[PCHUNK];
    int t = threadIdx.x;
    int base = blockIdx.x * PCHUNK;
    int cnt = E - base; if (cnt > PCHUNK) cnt = PCHUNK;

    for (int b = t; b < 1024; b += PT) hist[b] = 0;
    __syncthreads();
    // stage A: bucket histogram (dst-only read)
    for (int i = t; i < cnt; i += PT)
        atomicAdd(&hist[dst[base + i] >> BSHIFT], 1);
    __syncthreads();
    // scan 1024 entries with 512 threads (pair-sum Hillis-Steele)
    int h0 = hist[2*t], h1 = hist[2*t+1];
    int pair = h0 + h1;
    scan_s[t] = pair;
    __syncthreads();
    for (int off = 1; off < PT; off <<= 1) {
        int add = (t >= off) ? scan_s[t - off] : 0;
        __syncthreads();
        scan_s[t] += add;
        __syncthreads();
    }
    int pbase = scan_s[t] - pair;
    lofs[2*t]   = pbase;
    lofs[2*t+1] = pbase + h0;
    __syncthreads();
    // claim global runs (one atomic per non-empty (block,bucket)), zero LDS cursors
    for (int b = t; b < 1024; b += PT) {
        int c = hist[b];
        gbase[b] = c > 0 ? atomicAdd(&bcur[b], c) : 0;
        lcur[b] = 0;
    }
    __syncthreads();
    // stage B: re-read edges, place into LDS bucket-sorted order + global addr
    for (int i = t; i < cnt; i += PT) {
        int e = base + i;
        int d = dst[e];
        int b = d >> BSHIFT;
        float2 ea = ((const float2*)eattr)[e];
        __half2 hv = __floats2half2_rn(ea.x, ea.y);
        unsigned int eb = *reinterpret_cast<unsigned int*>(&hv);
        int q = atomicAdd(&lcur[b], 1);
        int idx = lofs[b] + q;
        srecs[idx] = make_uint2(((unsigned int)src[e] << 8) | (unsigned int)(d & (BNODES-1)), eb);
        gaddr[idx] = (unsigned int)(gbase[b] + q);
    }
    __syncthreads();
    // stage C: write out (bucket-run coalesced)
    for (int i = t; i < cnt; i += PT)
        grecs[gaddr[i]] = srecs[i];
}

// ---------------- phase 2: per-bucket in-LDS node sort, in place ----------------
// in rec: .x=(src<<8)|dlow ; out rec: .x=src, .y=half2(eattr), node-sorted
__global__ void __launch_bounds__(256) k_fine(
    const int* __restrict__ row, uint2* recs, int N)
{
    __shared__ uint2 rin[FCAP];
    __shared__ uint2 rout[FCAP];
    __shared__ int lhist[256], lsc[256], lcur2[256];
    int b = blockIdx.x;
    int n0 = b << BSHIFT;
    int nend = n0 + BNODES; if (nend > N) nend = N;
    int bstart = row[n0], bend = row[nend];
    int cnt = bend - bstart;
    if (cnt > FCAP) cnt = FCAP;   // safety clamp (+14 sigma margin)
    int t = threadIdx.x;
    lhist[t] = 0;
    __syncthreads();
    for (int i = t; i < cnt; i += 256) {
        uint2 r = recs[bstart + i];
        rin[i] = r;
        atomicAdd(&lhist[r.x & (BNODES-1)], 1);
    }
    __syncthreads();
    int v = lhist[t];
    lsc[t] = v;
    __syncthreads();
    for (int off = 1; off < 256; off <<= 1) {
        int add = (t >= off) ? lsc[t - off] : 0;
        __syncthreads();
        lsc[t] += add;
        __syncthreads();
    }
    lcur2[t] = lsc[t] - v;   // exclusive start
    __syncthreads();
    for (int i = t; i < cnt; i += 256) {
        uint2 r = rin[i];
        int p = atomicAdd(&lcur2[r.x & (BNODES-1)], 1);
        rout[p] = make_uint2(r.x >> 8, r.y);
    }
    __syncthreads();
    for (int i = t; i < cnt; i += 256)
        recs[bstart + i] = rout[i];
}

// ---------------- per-(node,head) online-softmax aggregation ----------------
struct AggState { float m, s, acc[8]; };

__device__ __forceinline__ void agg_edge(
    AggState& st, const float* va, const float* xd,
    const float* w0, const float* w1, const float* at,
    float ea0, float ea1)
{
    float lg = 0.f;
#pragma unroll
    for (int o = 0; o < 8; o++) {
        float mv = va[o] + xd[o] + (w0[o]*ea0 + w1[o]*ea1);
        mv = mv > 0.f ? mv : 0.2f*mv;      // leaky_relu 0.2
        lg += mv * at[o];
    }
    float nm = fmaxf(st.m, lg);
    float sc = __expf(st.m - nm);
    float wv = __expf(lg - nm);
    st.s = st.s*sc + wv;
#pragma unroll
    for (int o = 0; o < 8; o++) st.acc[o] = st.acc[o]*sc + wv*va[o];
    st.m = nm;
}

__device__ __forceinline__ void agg_node_head(
    int n, int h,
    const int* __restrict__ row, const uint2* __restrict__ recs,
    const __half* __restrict__ xl, const float* __restrict__ xr,
    const float* __restrict__ we, const float* __restrict__ att,
    const float* __restrict__ bias, float* out)
{
    int kb = h*8;
    float xd[8], w0[8], w1[8], at[8];
    {
        const float4* xrp = (const float4*)(xr + (size_t)n*HO + kb);
        float4 d0 = xrp[0], d1 = xrp[1];
        xd[0]=d0.x; xd[1]=d0.y; xd[2]=d0.z; xd[3]=d0.w;
        xd[4]=d1.x; xd[5]=d1.y; xd[6]=d1.z; xd[7]=d1.w;
    }
#pragma unroll
    for (int o = 0; o < 8; o++) {
        w0[o] = we[2*(kb+o)];
        w1[o] = we[2*(kb+o)+1];
        at[o] = att[kb+o];
    }
    AggState st;
    st.m = -INFINITY; st.s = 0.f;
#pragma unroll
    for (int o = 0; o < 8; o++) st.acc[o] = 0.f;

    int i = row[n], end = row[n+1];
    for (; i + 4 <= end; i += 4) {
        uint2 rA = recs[i], rB = recs[i+1], rC = recs[i+2], rD = recs[i+3];
        float vA[8], vB[8], vC[8], vD[8];
        load_half8(xl + (size_t)rA.x*HO + kb, vA);
        load_half8(xl + (size_t)rB.x*HO + kb, vB);
        load_half8(xl + (size_t)rC.x*HO + kb, vC);
        load_half8(xl + (size_t)rD.x*HO + kb, vD);
        __half2 hA = *reinterpret_cast<__half2*>(&rA.y);
        __half2 hB = *reinterpret_cast<__half2*>(&rB.y);
        __half2 hC = *reinterpret_cast<__half2*>(&rC.y);
        __half2 hD = *reinterpret_cast<__half2*>(&rD.y);
        agg_edge(st, vA, xd, w0, w1, at, __low2float(hA), __high2float(hA));
        agg_edge(st, vB, xd, w0, w1, at, __low2float(hB), __high2float(hB));
        agg_edge(st, vC, xd, w0, w1, at, __low2float(hC), __high2float(hC));
        agg_edge(st, vD, xd, w0, w1, at, __low2float(hD), __high2float(hD));
    }
    for (; i < end; i++) {
        uint2 rA = recs[i];
        float vA[8];
        load_half8(xl + (size_t)rA.x*HO + kb, vA);
        __half2 hA = *reinterpret_cast<__half2*>(&rA.y);
        agg_edge(st, vA, xd, w0, w1, at, __low2float(hA), __high2float(hA));
    }
    float inv = 1.f/(st.s + 1e-16f);
#pragma unroll
    for (int o = 0; o < 8; o++) out[o] = st.acc[o]*inv + bias[kb+o];
}

// layer 1: + lrelu(0.1), write h buffer
__global__ void __launch_bounds__(256) node_agg_l1(
    const int* __restrict__ row, const uint2* __restrict__ recs,
    const __half* __restrict__ xl, const float* __restrict__ xr,
    const float* __restrict__ we, const float* __restrict__ att,
    const float* __restrict__ bias, float* __restrict__ hout, int N)
{
    int tid = blockIdx.x * 256 + threadIdx.x;
    int n = tid >> 1, h = tid & 1;
    if (n >= N) return;
    float out[8];
    agg_node_head(n, h, row, recs, xl, xr, we, att, bias, out);
    float4* hp = (float4*)(hout + (size_t)n*HO + h*8);
    hp[0] = make_float4(lrelu(out[0],0.1f), lrelu(out[1],0.1f), lrelu(out[2],0.1f), lrelu(out[3],0.1f));
    hp[1] = make_float4(lrelu(out[4],0.1f), lrelu(out[5],0.1f), lrelu(out[6],0.1f), lrelu(out[7],0.1f));
}

// transform h by layer-2 weights -> xl2(fp16), xr2(fp32)
__global__ void __launch_bounds__(256) node_transform(
    const float* __restrict__ hin,
    const float* __restrict__ wl2, const float* __restrict__ bl2,
    const float* __restrict__ wr2, const float* __restrict__ br2,
    __half* __restrict__ xl2, float* __restrict__ xr2, int N)
{
    int n = blockIdx.x * 256 + threadIdx.x;
    if (n >= N) return;
    float h[HO];
    const float4* hp = (const float4*)(hin + (size_t)n*HO);
#pragma unroll
    for (int q = 0; q < 4; q++) {
        float4 v = hp[q];
        h[4*q]=v.x; h[4*q+1]=v.y; h[4*q+2]=v.z; h[4*q+3]=v.w;
    }
    float ol[HO], orr[HO];
#pragma unroll
    for (int j = 0; j < HO; j++) {
        float a = bl2[j], b = br2[j];
#pragma unroll
        for (int k = 0; k < HO; k++) { a += wl2[HO*j+k]*h[k]; b += wr2[HO*j+k]*h[k]; }
        ol[j] = a; orr[j] = b;
    }
    store_half8(xl2 + (size_t)n*HO,     ol);
    store_half8(xl2 + (size_t)n*HO + 8, ol + 8);
    float4* xr4 = (float4*)(xr2 + (size_t)n*HO);
#pragma unroll
    for (int q = 0; q < 4; q++)
        xr4[q] = make_float4(orr[4*q], orr[4*q+1], orr[4*q+2], orr[4*q+3]);
}

// layer 2: aggregate (+bias, no act), block-reduce, write per-block partials[16]
__global__ void __launch_bounds__(256) node_agg_l2(
    const int* __restrict__ row, const uint2* __restrict__ recs,
    const __half* __restrict__ xl, const float* __restrict__ xr,
    const float* __restrict__ we, const float* __restrict__ att,
    const float* __restrict__ bias, float* __restrict__ partials, int N)
{
    int tid = blockIdx.x * 256 + threadIdx.x;
    int n = tid >> 1, h = tid & 1;
    float out[8];
    if (n < N) {
        agg_node_head(n, h, row, recs, xl, xr, we, att, bias, out);
    } else {
#pragma unroll
        for (int o = 0; o < 8; o++) out[o] = 0.f;
    }
#pragma unroll
    for (int off = 32; off >= 2; off >>= 1) {
#pragma unroll
        for (int o = 0; o < 8; o++) out[o] += __shfl_down(out[o], off, 64);
    }
    __shared__ float sm[4][2][8];
    int wave = threadIdx.x >> 6, lane = threadIdx.x & 63;
    if (lane < 2) {
#pragma unroll
        for (int o = 0; o < 8; o++) sm[wave][lane][o] = out[o];
    }
    __syncthreads();
    if (threadIdx.x < 16) {
        int hh = threadIdx.x >> 3, oo = threadIdx.x & 7;
        float t = sm[0][hh][oo] + sm[1][hh][oo] + sm[2][hh][oo] + sm[3][hh][oo];
        partials[(size_t)blockIdx.x*16 + hh*8 + oo] = t;
    }
}

// ---------------- final tail ----------------
__global__ void __launch_bounds__(64) final_mlp(
    const float* __restrict__ partials, int nparts,
    const float* __restrict__ meta,
    const float* __restrict__ sp1_w, const float* __restrict__ sp1_b,
    const float* __restrict__ sp2_w, const float* __restrict__ sp2_b,
    const float* __restrict__ me_w, const float* __restrict__ me_b,
    const float* __restrict__ fc1_w, const float* __restrict__ fc1_b,
    const float* __restrict__ fc2_w, const float* __restrict__ fc2_b,
    const float* __restrict__ fc3_w, const float* __restrict__ fc3_b,
    float* __restrict__ out)
{
    __shared__ float red[4][16];
    __shared__ float pool[16];
    __shared__ float s1[64], zb[24], z1[24], z2[8];
    int t = threadIdx.x;
    {
        int col = t & 15, r0 = t >> 4;
        float acc = 0.f;
        for (int r = r0; r < nparts; r += 4) acc += partials[(size_t)r*16 + col];
        red[r0][col] = acc;
    }
    __syncthreads();
    if (t < 16) pool[t] = red[0][t] + red[1][t] + red[2][t] + red[3][t];
    __syncthreads();
    {
        float acc = sp1_b[t];
        for (int k = 0; k < 16; k++) acc += pool[k]*sp1_w[t*16+k];
        s1[t] = lrelu(acc, 0.1f);
    }
    __syncthreads();
    if (t < 16) {
        float acc = sp2_b[t];
        for (int k = 0; k < 64; k++) acc += s1[k]*sp2_w[t*64+k];
        zb[t] = acc;
    } else if (t < 24) {
        int j = t - 16;
        float acc = me_b[j];
        for (int k = 0; k < 6; k++) acc += meta[k]*me_w[j*6+k];
        zb[t] = lrelu(acc, 0.1f);
    }
    __syncthreads();
    if (t < 24) {
        float acc = fc1_b[t];
        for (int k = 0; k < 24; k++) acc += zb[k]*fc1_w[t*24+k];
        z1[t] = lrelu(acc, 0.1f);
    }
    __syncthreads();
    if (t < 8) {
        float acc = fc2_b[t];
        for (int k = 0; k < 24; k++) acc += z1[k]*fc2_w[t*24+k];
        z2[t] = lrelu(acc, 0.1f);
    }
    __syncthreads();
    if (t == 0) {
        float z3[3]; float mxv = -1e30f;
        for (int j = 0; j < 3; j++) {
            float acc = fc3_b[j];
            for (int k = 0; k < 8; k++) acc += z2[k]*fc3_w[j*8+k];
            z3[j] = acc; mxv = fmaxf(mxv, acc);
        }
        float s = 0.f;
        for (int j = 0; j < 3; j++) { z3[j] = __expf(z3[j]-mxv); s += z3[j]; }
        for (int j = 0; j < 3; j++) out[j] = z3[j]/s;
    }
}

extern "C" void kernel_launch(void* const* d_in, const int* in_sizes, int n_in,
                              void* d_out, int out_size, void* d_ws, size_t ws_size,
                              hipStream_t stream)
{
    const float* x      = (const float*)d_in[0];
    const int*   eidx   = (const int*)  d_in[1];
    const float* eattr  = (const float*)d_in[2];
    const float* meta   = (const float*)d_in[3];
    const float* ft1_w  = (const float*)d_in[4];
    const float* ft1_b  = (const float*)d_in[5];
    const float* ft2_w  = (const float*)d_in[6];
    const float* ft2_b  = (const float*)d_in[7];
    const float* g1_wl  = (const float*)d_in[8];
    const float* g1_bl  = (const float*)d_in[9];
    const float* g1_wr  = (const float*)d_in[10];
    const float* g1_br  = (const float*)d_in[11];
    const float* g1_we  = (const float*)d_in[12];
    const float* g1_att = (const float*)d_in[13];
    const float* g1_bias= (const float*)d_in[14];
    const float* g2_wl  = (const float*)d_in[15];
    const float* g2_bl  = (const float*)d_in[16];
    const float* g2_wr  = (const float*)d_in[17];
    const float* g2_br  = (const float*)d_in[18];
    const float* g2_we  = (const float*)d_in[19];
    const float* g2_att = (const float*)d_in[20];
    const float* g2_bias= (const float*)d_in[21];
    const float* sp1_w  = (const float*)d_in[22];
    const float* sp1_b  = (const float*)d_in[23];
    const float* sp2_w  = (const float*)d_in[24];
    const float* sp2_b  = (const float*)d_in[25];
    const float* me_w   = (const float*)d_in[26];
    const float* me_b   = (const float*)d_in[27];
    const float* fc1_w  = (const float*)d_in[28];
    const float* fc1_b  = (const float*)d_in[29];
    const float* fc2_w  = (const float*)d_in[30];
    const float* fc2_b  = (const float*)d_in[31];
    const float* fc3_w  = (const float*)d_in[32];
    const float* fc3_b  = (const float*)d_in[33];
    float* out = (float*)d_out;

    const int N = in_sizes[0] / 3;
    const int E = in_sizes[2] / 2;
    const int* src = eidx;
    const int* dst = eidx + E;

    const int BN    = (N + 255) / 256;
    const int BE    = (E + 255) / 256;
    const int BN2   = (2*N + 255) / 256;          // agg kernels: 2 threads/node
    const int nb    = BN;                          // <= 1024
    const int NBUCK = (N + BNODES - 1) >> BSHIFT;  // 977
    const int BP    = (E + PCHUNK - 1) / PCHUNK;   // k_part blocks

    // workspace layout (256B-aligned):
    char* w = (char*)d_ws;
    size_t off = 0;
    auto take = [&](size_t bytes) { size_t o = off; off += (bytes + 255) & ~(size_t)255; return o; };
    int*    row      = (int*)   (w + take((size_t)4*(N+1)));
    int*    deg      = (int*)   (w + take((size_t)4*N));
    int*    bsum     = (int*)   (w + take(4096));
    int*    bcur     = (int*)   (w + take(4096));
    float*  partials = (float*) (w + take((size_t)4*16*BN2));
    uint2*  recs     = (uint2*) (w + take((size_t)8*E));
    __half* xl       = (__half*)(w + take((size_t)32*N));   // fp16 node table
    float*  xr       = (float*) (w + take((size_t)64*N));
    float*  hbuf     = (float*) (w + take((size_t)64*N));
    // total ~= 2MB + 40MB + 8MB + 32MB ~= 82MB

    hipMemsetAsync(deg, 0, (size_t)4*N, stream);

    // node features + layer-1 transforms
    node_l1<<<BN, 256, 0, stream>>>(x, ft1_w, ft1_b, ft2_w, ft2_b,
                                    g1_wl, g1_bl, g1_wr, g1_br, xl, xr, N);
    // CSR row + two-phase dst-sort of packed edge records (graph-only)
    k_hist<<<BE, 256, 0, stream>>>(dst, deg, E);
    k_scanA<<<nb, 256, 0, stream>>>(deg, bsum, N);
    k_scanB<<<1, 1024, 0, stream>>>(bsum, nb);
    k_scanC<<<nb, 256, 0, stream>>>(deg, bsum, row, N, E);
    k_binit<<<(NBUCK + 255)/256, 256, 0, stream>>>(row, bcur, NBUCK, N);
    k_part<<<BP, PT, 0, stream>>>(src, dst, eattr, bcur, recs, E);
    k_fine<<<NBUCK, 256, 0, stream>>>(row, recs, N);

    // ---- layer 1 ----
    node_agg_l1<<<BN2, 256, 0, stream>>>(row, recs, xl, xr,
                                         g1_we, g1_att, g1_bias, hbuf, N);
    node_transform<<<BN, 256, 0, stream>>>(hbuf, g2_wl, g2_bl, g2_wr, g2_br, xl, xr, N);
    // ---- layer 2 ----
    node_agg_l2<<<BN2, 256, 0, stream>>>(row, recs, xl, xr,
                                         g2_we, g2_att, g2_bias, partials, N);
    // ---- tail ----
    final_mlp<<<1, 64, 0, stream>>>(partials, BN2, meta, sp1_w, sp1_b, sp2_w, sp2_b,
                                    me_w, me_b, fc1_w, fc1_b, fc2_w, fc2_b,
                                    fc3_w, fc3_b, out);
}

// Round 8
// 610.162 us; speedup vs baseline: 4.0205x; 1.2984x over previous
//
#include <hip/hip_runtime.h>
#include <hip/hip_bf16.h>
#include <hip/hip_fp16.h>
#include <math.h>

// SportsGNN: ftMLP -> GATv2 x2 -> sumpool -> MLP -> softmax
// N=250000, E=5000000, H=2, O=8 (HO=16)
// Round-8: round-7 minus the per-node global histogram. Bucket-level
// histogram (LDS pre-agg, 4KB target) + k_fine emits per-node row[] from
// its in-LDS scan. k_part / agg kernels unchanged from round 7.

#define HO 16
#define BSHIFT 8
#define BNODES 256
#define PT 512          // k_part/k_bhist threads
#define PCHUNK 8192     // edges per partition block
#define FCAP 6144       // k_fine LDS record capacity (mean ~5117, sigma ~72)

__device__ __forceinline__ float lrelu(float x, float s) { return x > 0.f ? x : s * x; }

// pack 8 floats -> 16B of fp16 at p (16B aligned)
__device__ __forceinline__ void store_half8(__half* p, const float* v) {
    __half2 hx[4];
#pragma unroll
    for (int q = 0; q < 4; q++) hx[q] = __floats2half2_rn(v[2*q], v[2*q+1]);
    *reinterpret_cast<uint4*>(p) = *reinterpret_cast<uint4*>(hx);
}

// load 16B of fp16 -> 8 floats
__device__ __forceinline__ void load_half8(const __half* p, float* v) {
    uint4 u = *reinterpret_cast<const uint4*>(p);
    const __half2* h2 = reinterpret_cast<const __half2*>(&u);
#pragma unroll
    for (int q = 0; q < 4; q++) {
        float2 f = __half22float2(h2[q]);
        v[2*q] = f.x; v[2*q+1] = f.y;
    }
}

// ---------------- node kernel, layer 1: x[N,3] -> ftMLP -> xl1(fp16),xr1(fp32) ----------------
__global__ void __launch_bounds__(256) node_l1(
    const float* __restrict__ x,
    const float* __restrict__ ft1_w, const float* __restrict__ ft1_b,
    const float* __restrict__ ft2_w, const float* __restrict__ ft2_b,
    const float* __restrict__ wl, const float* __restrict__ bl,
    const float* __restrict__ wr, const float* __restrict__ br,
    __half* __restrict__ xl, float* __restrict__ xr, int N)
{
    int n = blockIdx.x * 256 + threadIdx.x;
    if (n >= N) return;
    float x0 = x[3*n], x1 = x[3*n+1], x2 = x[3*n+2];
    float h1[8];
#pragma unroll
    for (int j = 0; j < 8; j++) {
        float a = ft1_w[3*j]*x0 + ft1_w[3*j+1]*x1 + ft1_w[3*j+2]*x2 + ft1_b[j];
        h1[j] = lrelu(a, 0.1f);
    }
    float h2[8];
#pragma unroll
    for (int j = 0; j < 8; j++) {
        float a = ft2_b[j];
#pragma unroll
        for (int k = 0; k < 8; k++) a += ft2_w[8*j+k]*h1[k];
        h2[j] = lrelu(a, 0.1f);
    }
    float ol[HO], orr[HO];
#pragma unroll
    for (int j = 0; j < HO; j++) {
        float a = bl[j], b = br[j];
#pragma unroll
        for (int k = 0; k < 8; k++) { a += wl[8*j+k]*h2[k]; b += wr[8*j+k]*h2[k]; }
        ol[j] = a; orr[j] = b;
    }
    store_half8(xl + (size_t)n*HO,     ol);
    store_half8(xl + (size_t)n*HO + 8, ol + 8);
    float4* xr4 = (float4*)(xr + (size_t)n*HO);
#pragma unroll
    for (int q = 0; q < 4; q++)
        xr4[q] = make_float4(orr[4*q], orr[4*q+1], orr[4*q+2], orr[4*q+3]);
}

// ---------------- bucket histogram (LDS pre-aggregated) ----------------
__global__ void __launch_bounds__(PT) k_bhist(
    const int* __restrict__ dst, int* __restrict__ bcnt, int E)
{
    __shared__ int hist[1024];
    int t = threadIdx.x;
    int base = blockIdx.x * PCHUNK;
    int cnt = E - base; if (cnt > PCHUNK) cnt = PCHUNK;
    for (int b = t; b < 1024; b += PT) hist[b] = 0;
    __syncthreads();
    for (int i = t; i < cnt; i += PT)
        atomicAdd(&hist[dst[base + i] >> BSHIFT], 1);
    __syncthreads();
    for (int b = t; b < 1024; b += PT) {
        int c = hist[b];
        if (c > 0) atomicAdd(&bcnt[b], c);
    }
}

// exclusive scan of bucket counts (nb <= 1024); writes boff (+boff[nb]=E) and bcur
__global__ void __launch_bounds__(1024) k_bscan(
    const int* __restrict__ bcnt, int* __restrict__ boff, int* __restrict__ bcur,
    int nb, int E)
{
    __shared__ int s[1024];
    int t = threadIdx.x;
    int v = (t < nb) ? bcnt[t] : 0;
    s[t] = v;
    __syncthreads();
    for (int off = 1; off < 1024; off <<= 1) {
        int a = (t >= off) ? s[t - off] : 0;
        __syncthreads();
        s[t] += a;
        __syncthreads();
    }
    if (t < nb) { int ex = s[t] - v; boff[t] = ex; bcur[t] = ex; }
    if (t == 0) boff[nb] = E;
}

// ---------------- phase 1: LDS multisplit into buckets ----------------
// out rec: .x = (src<<8)|(dst&255), .y = half2(eattr)
__global__ void __launch_bounds__(PT) k_part(
    const int* __restrict__ src, const int* __restrict__ dst,
    const float* __restrict__ eattr, int* __restrict__ bcur,
    uint2* __restrict__ grecs, int E)
{
    __shared__ int hist[1024], lofs[1024], gbase[1024], lcur[1024];
    __shared__ int scan_s[PT];
    __shared__ uint2 srecs[PCHUNK];
    __shared__ unsigned int gaddr[PCHUNK];
    int t = threadIdx.x;
    int base = blockIdx.x * PCHUNK;
    int cnt = E - base; if (cnt > PCHUNK) cnt = PCHUNK;

    for (int b = t; b < 1024; b += PT) hist[b] = 0;
    __syncthreads();
    // stage A: bucket histogram (dst-only read)
    for (int i = t; i < cnt; i += PT)
        atomicAdd(&hist[dst[base + i] >> BSHIFT], 1);
    __syncthreads();
    // scan 1024 entries with 512 threads (pair-sum Hillis-Steele)
    int h0 = hist[2*t], h1 = hist[2*t+1];
    int pair = h0 + h1;
    scan_s[t] = pair;
    __syncthreads();
    for (int off = 1; off < PT; off <<= 1) {
        int add = (t >= off) ? scan_s[t - off] : 0;
        __syncthreads();
        scan_s[t] += add;
        __syncthreads();
    }
    int pbase = scan_s[t] - pair;
    lofs[2*t]   = pbase;
    lofs[2*t+1] = pbase + h0;
    __syncthreads();
    // claim global runs (one atomic per non-empty (block,bucket)), zero LDS cursors
    for (int b = t; b < 1024; b += PT) {
        int c = hist[b];
        gbase[b] = c > 0 ? atomicAdd(&bcur[b], c) : 0;
        lcur[b] = 0;
    }
    __syncthreads();
    // stage B: re-read edges, place into LDS bucket-sorted order + global addr
    for (int i = t; i < cnt; i += PT) {
        int e = base + i;
        int d = dst[e];
        int b = d >> BSHIFT;
        float2 ea = ((const float2*)eattr)[e];
        __half2 hv = __floats2half2_rn(ea.x, ea.y);
        unsigned int eb = *reinterpret_cast<unsigned int*>(&hv);
        int q = atomicAdd(&lcur[b], 1);
        int idx = lofs[b] + q;
        srecs[idx] = make_uint2(((unsigned int)src[e] << 8) | (unsigned int)(d & (BNODES-1)), eb);
        gaddr[idx] = (unsigned int)(gbase[b] + q);
    }
    __syncthreads();
    // stage C: write out (bucket-run coalesced)
    for (int i = t; i < cnt; i += PT)
        grecs[gaddr[i]] = srecs[i];
}

// ---------------- phase 2: per-bucket in-LDS node sort + row emission ----------------
// in rec: .x=(src<<8)|dlow ; out rec: .x=src, .y=half2(eattr), node-sorted.
// Also writes row[n] = bucket_start + exclusive in-bucket prefix (coalesced).
__global__ void __launch_bounds__(256) k_fine(
    const int* __restrict__ boff, uint2* recs, int* __restrict__ row, int N, int E)
{
    __shared__ uint2 rin[FCAP];
    __shared__ uint2 rout[FCAP];
    __shared__ int lhist[256], lsc[256], lcur2[256];
    int b = blockIdx.x;
    int bstart = boff[b], bend = boff[b+1];
    int cnt = bend - bstart;
    if (cnt > FCAP) cnt = FCAP;   // safety clamp (+14 sigma margin)
    int t = threadIdx.x;
    lhist[t] = 0;
    __syncthreads();
    for (int i = t; i < cnt; i += 256) {
        uint2 r = recs[bstart + i];
        rin[i] = r;
        atomicAdd(&lhist[r.x & (BNODES-1)], 1);
    }
    __syncthreads();
    int v = lhist[t];
    lsc[t] = v;
    __syncthreads();
    for (int off = 1; off < 256; off <<= 1) {
        int add = (t >= off) ? lsc[t - off] : 0;
        __syncthreads();
        lsc[t] += add;
        __syncthreads();
    }
    int ex = lsc[t] - v;      // exclusive in-bucket prefix
    lcur2[t] = ex;
    int n = (b << BSHIFT) + t;
    if (n < N) row[n] = bstart + ex;
    if (n == N - 1) row[N] = E;
    __syncthreads();
    for (int i = t; i < cnt; i += 256) {
        uint2 r = rin[i];
        int p = atomicAdd(&lcur2[r.x & (BNODES-1)], 1);
        rout[p] = make_uint2(r.x >> 8, r.y);
    }
    __syncthreads();
    for (int i = t; i < cnt; i += 256)
        recs[bstart + i] = rout[i];
}

// ---------------- per-(node,head) online-softmax aggregation ----------------
struct AggState { float m, s, acc[8]; };

__device__ __forceinline__ void agg_edge(
    AggState& st, const float* va, const float* xd,
    const float* w0, const float* w1, const float* at,
    float ea0, float ea1)
{
    float lg = 0.f;
#pragma unroll
    for (int o = 0; o < 8; o++) {
        float mv = va[o] + xd[o] + (w0[o]*ea0 + w1[o]*ea1);
        mv = mv > 0.f ? mv : 0.2f*mv;      // leaky_relu 0.2
        lg += mv * at[o];
    }
    float nm = fmaxf(st.m, lg);
    float sc = __expf(st.m - nm);
    float wv = __expf(lg - nm);
    st.s = st.s*sc + wv;
#pragma unroll
    for (int o = 0; o < 8; o++) st.acc[o] = st.acc[o]*sc + wv*va[o];
    st.m = nm;
}

__device__ __forceinline__ void agg_node_head(
    int n, int h,
    const int* __restrict__ row, const uint2* __restrict__ recs,
    const __half* __restrict__ xl, const float* __restrict__ xr,
    const float* __restrict__ we, const float* __restrict__ att,
    const float* __restrict__ bias, float* out)
{
    int kb = h*8;
    float xd[8], w0[8], w1[8], at[8];
    {
        const float4* xrp = (const float4*)(xr + (size_t)n*HO + kb);
        float4 d0 = xrp[0], d1 = xrp[1];
        xd[0]=d0.x; xd[1]=d0.y; xd[2]=d0.z; xd[3]=d0.w;
        xd[4]=d1.x; xd[5]=d1.y; xd[6]=d1.z; xd[7]=d1.w;
    }
#pragma unroll
    for (int o = 0; o < 8; o++) {
        w0[o] = we[2*(kb+o)];
        w1[o] = we[2*(kb+o)+1];
        at[o] = att[kb+o];
    }
    AggState st;
    st.m = -INFINITY; st.s = 0.f;
#pragma unroll
    for (int o = 0; o < 8; o++) st.acc[o] = 0.f;

    int i = row[n], end = row[n+1];
    for (; i + 4 <= end; i += 4) {
        uint2 rA = recs[i], rB = recs[i+1], rC = recs[i+2], rD = recs[i+3];
        float vA[8], vB[8], vC[8], vD[8];
        load_half8(xl + (size_t)rA.x*HO + kb, vA);
        load_half8(xl + (size_t)rB.x*HO + kb, vB);
        load_half8(xl + (size_t)rC.x*HO + kb, vC);
        load_half8(xl + (size_t)rD.x*HO + kb, vD);
        __half2 hA = *reinterpret_cast<__half2*>(&rA.y);
        __half2 hB = *reinterpret_cast<__half2*>(&rB.y);
        __half2 hC = *reinterpret_cast<__half2*>(&rC.y);
        __half2 hD = *reinterpret_cast<__half2*>(&rD.y);
        agg_edge(st, vA, xd, w0, w1, at, __low2float(hA), __high2float(hA));
        agg_edge(st, vB, xd, w0, w1, at, __low2float(hB), __high2float(hB));
        agg_edge(st, vC, xd, w0, w1, at, __low2float(hC), __high2float(hC));
        agg_edge(st, vD, xd, w0, w1, at, __low2float(hD), __high2float(hD));
    }
    for (; i < end; i++) {
        uint2 rA = recs[i];
        float vA[8];
        load_half8(xl + (size_t)rA.x*HO + kb, vA);
        __half2 hA = *reinterpret_cast<__half2*>(&rA.y);
        agg_edge(st, vA, xd, w0, w1, at, __low2float(hA), __high2float(hA));
    }
    float inv = 1.f/(st.s + 1e-16f);
#pragma unroll
    for (int o = 0; o < 8; o++) out[o] = st.acc[o]*inv + bias[kb+o];
}

// layer 1: + lrelu(0.1), write h buffer
__global__ void __launch_bounds__(256) node_agg_l1(
    const int* __restrict__ row, const uint2* __restrict__ recs,
    const __half* __restrict__ xl, const float* __restrict__ xr,
    const float* __restrict__ we, const float* __restrict__ att,
    const float* __restrict__ bias, float* __restrict__ hout, int N)
{
    int tid = blockIdx.x * 256 + threadIdx.x;
    int n = tid >> 1, h = tid & 1;
    if (n >= N) return;
    float out[8];
    agg_node_head(n, h, row, recs, xl, xr, we, att, bias, out);
    float4* hp = (float4*)(hout + (size_t)n*HO + h*8);
    hp[0] = make_float4(lrelu(out[0],0.1f), lrelu(out[1],0.1f), lrelu(out[2],0.1f), lrelu(out[3],0.1f));
    hp[1] = make_float4(lrelu(out[4],0.1f), lrelu(out[5],0.1f), lrelu(out[6],0.1f), lrelu(out[7],0.1f));
}

// transform h by layer-2 weights -> xl2(fp16), xr2(fp32)
__global__ void __launch_bounds__(256) node_transform(
    const float* __restrict__ hin,
    const float* __restrict__ wl2, const float* __restrict__ bl2,
    const float* __restrict__ wr2, const float* __restrict__ br2,
    __half* __restrict__ xl2, float* __restrict__ xr2, int N)
{
    int n = blockIdx.x * 256 + threadIdx.x;
    if (n >= N) return;
    float h[HO];
    const float4* hp = (const float4*)(hin + (size_t)n*HO);
#pragma unroll
    for (int q = 0; q < 4; q++) {
        float4 v = hp[q];
        h[4*q]=v.x; h[4*q+1]=v.y; h[4*q+2]=v.z; h[4*q+3]=v.w;
    }
    float ol[HO], orr[HO];
#pragma unroll
    for (int j = 0; j < HO; j++) {
        float a = bl2[j], b = br2[j];
#pragma unroll
        for (int k = 0; k < HO; k++) { a += wl2[HO*j+k]*h[k]; b += wr2[HO*j+k]*h[k]; }
        ol[j] = a; orr[j] = b;
    }
    store_half8(xl2 + (size_t)n*HO,     ol);
    store_half8(xl2 + (size_t)n*HO + 8, ol + 8);
    float4* xr4 = (float4*)(xr2 + (size_t)n*HO);
#pragma unroll
    for (int q = 0; q < 4; q++)
        xr4[q] = make_float4(orr[4*q], orr[4*q+1], orr[4*q+2], orr[4*q+3]);
}

// layer 2: aggregate (+bias, no act), block-reduce, write per-block partials[16]
__global__ void __launch_bounds__(256) node_agg_l2(
    const int* __restrict__ row, const uint2* __restrict__ recs,
    const __half* __restrict__ xl, const float* __restrict__ xr,
    const float* __restrict__ we, const float* __restrict__ att,
    const float* __restrict__ bias, float* __restrict__ partials, int N)
{
    int tid = blockIdx.x * 256 + threadIdx.x;
    int n = tid >> 1, h = tid & 1;
    float out[8];
    if (n < N) {
        agg_node_head(n, h, row, recs, xl, xr, we, att, bias, out);
    } else {
#pragma unroll
        for (int o = 0; o < 8; o++) out[o] = 0.f;
    }
#pragma unroll
    for (int off = 32; off >= 2; off >>= 1) {
#pragma unroll
        for (int o = 0; o < 8; o++) out[o] += __shfl_down(out[o], off, 64);
    }
    __shared__ float sm[4][2][8];
    int wave = threadIdx.x >> 6, lane = threadIdx.x & 63;
    if (lane < 2) {
#pragma unroll
        for (int o = 0; o < 8; o++) sm[wave][lane][o] = out[o];
    }
    __syncthreads();
    if (threadIdx.x < 16) {
        int hh = threadIdx.x >> 3, oo = threadIdx.x & 7;
        float t = sm[0][hh][oo] + sm[1][hh][oo] + sm[2][hh][oo] + sm[3][hh][oo];
        partials[(size_t)blockIdx.x*16 + hh*8 + oo] = t;
    }
}

// ---------------- final tail ----------------
__global__ void __launch_bounds__(64) final_mlp(
    const float* __restrict__ partials, int nparts,
    const float* __restrict__ meta,
    const float* __restrict__ sp1_w, const float* __restrict__ sp1_b,
    const float* __restrict__ sp2_w, const float* __restrict__ sp2_b,
    const float* __restrict__ me_w, const float* __restrict__ me_b,
    const float* __restrict__ fc1_w, const float* __restrict__ fc1_b,
    const float* __restrict__ fc2_w, const float* __restrict__ fc2_b,
    const float* __restrict__ fc3_w, const float* __restrict__ fc3_b,
    float* __restrict__ out)
{
    __shared__ float red[4][16];
    __shared__ float pool[16];
    __shared__ float s1[64], zb[24], z1[24], z2[8];
    int t = threadIdx.x;
    {
        int col = t & 15, r0 = t >> 4;
        float acc = 0.f;
        for (int r = r0; r < nparts; r += 4) acc += partials[(size_t)r*16 + col];
        red[r0][col] = acc;
    }
    __syncthreads();
    if (t < 16) pool[t] = red[0][t] + red[1][t] + red[2][t] + red[3][t];
    __syncthreads();
    {
        float acc = sp1_b[t];
        for (int k = 0; k < 16; k++) acc += pool[k]*sp1_w[t*16+k];
        s1[t] = lrelu(acc, 0.1f);
    }
    __syncthreads();
    if (t < 16) {
        float acc = sp2_b[t];
        for (int k = 0; k < 64; k++) acc += s1[k]*sp2_w[t*64+k];
        zb[t] = acc;
    } else if (t < 24) {
        int j = t - 16;
        float acc = me_b[j];
        for (int k = 0; k < 6; k++) acc += meta[k]*me_w[j*6+k];
        zb[t] = lrelu(acc, 0.1f);
    }
    __syncthreads();
    if (t < 24) {
        float acc = fc1_b[t];
        for (int k = 0; k < 24; k++) acc += zb[k]*fc1_w[t*24+k];
        z1[t] = lrelu(acc, 0.1f);
    }
    __syncthreads();
    if (t < 8) {
        float acc = fc2_b[t];
        for (int k = 0; k < 24; k++) acc += z1[k]*fc2_w[t*24+k];
        z2[t] = lrelu(acc, 0.1f);
    }
    __syncthreads();
    if (t == 0) {
        float z3[3]; float mxv = -1e30f;
        for (int j = 0; j < 3; j++) {
            float acc = fc3_b[j];
            for (int k = 0; k < 8; k++) acc += z2[k]*fc3_w[j*8+k];
            z3[j] = acc; mxv = fmaxf(mxv, acc);
        }
        float s = 0.f;
        for (int j = 0; j < 3; j++) { z3[j] = __expf(z3[j]-mxv); s += z3[j]; }
        for (int j = 0; j < 3; j++) out[j] = z3[j]/s;
    }
}

extern "C" void kernel_launch(void* const* d_in, const int* in_sizes, int n_in,
                              void* d_out, int out_size, void* d_ws, size_t ws_size,
                              hipStream_t stream)
{
    const float* x      = (const float*)d_in[0];
    const int*   eidx   = (const int*)  d_in[1];
    const float* eattr  = (const float*)d_in[2];
    const float* meta   = (const float*)d_in[3];
    const float* ft1_w  = (const float*)d_in[4];
    const float* ft1_b  = (const float*)d_in[5];
    const float* ft2_w  = (const float*)d_in[6];
    const float* ft2_b  = (const float*)d_in[7];
    const float* g1_wl  = (const float*)d_in[8];
    const float* g1_bl  = (const float*)d_in[9];
    const float* g1_wr  = (const float*)d_in[10];
    const float* g1_br  = (const float*)d_in[11];
    const float* g1_we  = (const float*)d_in[12];
    const float* g1_att = (const float*)d_in[13];
    const float* g1_bias= (const float*)d_in[14];
    const float* g2_wl  = (const float*)d_in[15];
    const float* g2_bl  = (const float*)d_in[16];
    const float* g2_wr  = (const float*)d_in[17];
    const float* g2_br  = (const float*)d_in[18];
    const float* g2_we  = (const float*)d_in[19];
    const float* g2_att = (const float*)d_in[20];
    const float* g2_bias= (const float*)d_in[21];
    const float* sp1_w  = (const float*)d_in[22];
    const float* sp1_b  = (const float*)d_in[23];
    const float* sp2_w  = (const float*)d_in[24];
    const float* sp2_b  = (const float*)d_in[25];
    const float* me_w   = (const float*)d_in[26];
    const float* me_b   = (const float*)d_in[27];
    const float* fc1_w  = (const float*)d_in[28];
    const float* fc1_b  = (const float*)d_in[29];
    const float* fc2_w  = (const float*)d_in[30];
    const float* fc2_b  = (const float*)d_in[31];
    const float* fc3_w  = (const float*)d_in[32];
    const float* fc3_b  = (const float*)d_in[33];
    float* out = (float*)d_out;

    const int N = in_sizes[0] / 3;
    const int E = in_sizes[2] / 2;
    const int* src = eidx;
    const int* dst = eidx + E;

    const int BN    = (N + 255) / 256;
    const int BN2   = (2*N + 255) / 256;          // agg kernels: 2 threads/node
    const int NBUCK = (N + BNODES - 1) >> BSHIFT;  // 977 (<= 1024)
    const int BP    = (E + PCHUNK - 1) / PCHUNK;   // partition blocks

    // workspace layout (256B-aligned):
    char* w = (char*)d_ws;
    size_t off = 0;
    auto take = [&](size_t bytes) { size_t o = off; off += (bytes + 255) & ~(size_t)255; return o; };
    int*    row      = (int*)   (w + take((size_t)4*(N+1)));
    int*    bcnt     = (int*)   (w + take(4096));
    int*    boff     = (int*)   (w + take(4096 + 4));
    int*    bcur     = (int*)   (w + take(4096));
    float*  partials = (float*) (w + take((size_t)4*16*BN2));
    uint2*  recs     = (uint2*) (w + take((size_t)8*E));
    __half* xl       = (__half*)(w + take((size_t)32*N));   // fp16 node table
    float*  xr       = (float*) (w + take((size_t)64*N));
    float*  hbuf     = (float*) (w + take((size_t)64*N));
    // total ~= 1MB + 40MB + 8MB + 32MB ~= 81MB

    hipMemsetAsync(bcnt, 0, 4096, stream);

    // node features + layer-1 transforms
    node_l1<<<BN, 256, 0, stream>>>(x, ft1_w, ft1_b, ft2_w, ft2_b,
                                    g1_wl, g1_bl, g1_wr, g1_br, xl, xr, N);
    // bucket histogram + scan + two-phase dst-sort (graph-only; shared by both layers)
    k_bhist<<<BP, PT, 0, stream>>>(dst, bcnt, E);
    k_bscan<<<1, 1024, 0, stream>>>(bcnt, boff, bcur, NBUCK, E);
    k_part<<<BP, PT, 0, stream>>>(src, dst, eattr, bcur, recs, E);
    k_fine<<<NBUCK, 256, 0, stream>>>(boff, recs, row, N, E);

    // ---- layer 1 ----
    node_agg_l1<<<BN2, 256, 0, stream>>>(row, recs, xl, xr,
                                         g1_we, g1_att, g1_bias, hbuf, N);
    node_transform<<<BN, 256, 0, stream>>>(hbuf, g2_wl, g2_bl, g2_wr, g2_br, xl, xr, N);
    // ---- layer 2 ----
    node_agg_l2<<<BN2, 256, 0, stream>>>(row, recs, xl, xr,
                                         g2_we, g2_att, g2_bias, partials, N);
    // ---- tail ----
    final_mlp<<<1, 64, 0, stream>>>(partials, BN2, meta, sp1_w, sp1_b, sp2_w, sp2_b,
                                    me_w, me_b, fc1_w, fc1_b, fc2_w, fc2_b,
                                    fc3_w, fc3_b, out);
}

// Round 9
// 505.410 us; speedup vs baseline: 4.8538x; 1.2073x over previous
//
#include <hip/hip_runtime.h>
#include <hip/hip_bf16.h>
#include <hip/hip_fp16.h>
#include <math.h>

// SportsGNN: ftMLP -> GATv2 x2 -> sumpool -> MLP -> softmax
// N=250000, E=5000000, H=2, O=8 (HO=16)
// Round-9: round-8 + parallel partials reduction (k_reduce, 16 blocks) replacing
// the single-wave fold inside final_mlp (was 122 us of serial load latency).
// partials now column-major for coalesced per-column reduction.

#define HO 16
#define BSHIFT 8
#define BNODES 256
#define PT 512          // k_part/k_bhist threads
#define PCHUNK 8192     // edges per partition block
#define FCAP 6144       // k_fine LDS record capacity (mean ~5117, sigma ~72)

__device__ __forceinline__ float lrelu(float x, float s) { return x > 0.f ? x : s * x; }

// pack 8 floats -> 16B of fp16 at p (16B aligned)
__device__ __forceinline__ void store_half8(__half* p, const float* v) {
    __half2 hx[4];
#pragma unroll
    for (int q = 0; q < 4; q++) hx[q] = __floats2half2_rn(v[2*q], v[2*q+1]);
    *reinterpret_cast<uint4*>(p) = *reinterpret_cast<uint4*>(hx);
}

// load 16B of fp16 -> 8 floats
__device__ __forceinline__ void load_half8(const __half* p, float* v) {
    uint4 u = *reinterpret_cast<const uint4*>(p);
    const __half2* h2 = reinterpret_cast<const __half2*>(&u);
#pragma unroll
    for (int q = 0; q < 4; q++) {
        float2 f = __half22float2(h2[q]);
        v[2*q] = f.x; v[2*q+1] = f.y;
    }
}

// ---------------- node kernel, layer 1: x[N,3] -> ftMLP -> xl1(fp16),xr1(fp32) ----------------
__global__ void __launch_bounds__(256) node_l1(
    const float* __restrict__ x,
    const float* __restrict__ ft1_w, const float* __restrict__ ft1_b,
    const float* __restrict__ ft2_w, const float* __restrict__ ft2_b,
    const float* __restrict__ wl, const float* __restrict__ bl,
    const float* __restrict__ wr, const float* __restrict__ br,
    __half* __restrict__ xl, float* __restrict__ xr, int N)
{
    int n = blockIdx.x * 256 + threadIdx.x;
    if (n >= N) return;
    float x0 = x[3*n], x1 = x[3*n+1], x2 = x[3*n+2];
    float h1[8];
#pragma unroll
    for (int j = 0; j < 8; j++) {
        float a = ft1_w[3*j]*x0 + ft1_w[3*j+1]*x1 + ft1_w[3*j+2]*x2 + ft1_b[j];
        h1[j] = lrelu(a, 0.1f);
    }
    float h2[8];
#pragma unroll
    for (int j = 0; j < 8; j++) {
        float a = ft2_b[j];
#pragma unroll
        for (int k = 0; k < 8; k++) a += ft2_w[8*j+k]*h1[k];
        h2[j] = lrelu(a, 0.1f);
    }
    float ol[HO], orr[HO];
#pragma unroll
    for (int j = 0; j < HO; j++) {
        float a = bl[j], b = br[j];
#pragma unroll
        for (int k = 0; k < 8; k++) { a += wl[8*j+k]*h2[k]; b += wr[8*j+k]*h2[k]; }
        ol[j] = a; orr[j] = b;
    }
    store_half8(xl + (size_t)n*HO,     ol);
    store_half8(xl + (size_t)n*HO + 8, ol + 8);
    float4* xr4 = (float4*)(xr + (size_t)n*HO);
#pragma unroll
    for (int q = 0; q < 4; q++)
        xr4[q] = make_float4(orr[4*q], orr[4*q+1], orr[4*q+2], orr[4*q+3]);
}

// ---------------- bucket histogram (LDS pre-aggregated) ----------------
__global__ void __launch_bounds__(PT) k_bhist(
    const int* __restrict__ dst, int* __restrict__ bcnt, int E)
{
    __shared__ int hist[1024];
    int t = threadIdx.x;
    int base = blockIdx.x * PCHUNK;
    int cnt = E - base; if (cnt > PCHUNK) cnt = PCHUNK;
    for (int b = t; b < 1024; b += PT) hist[b] = 0;
    __syncthreads();
    for (int i = t; i < cnt; i += PT)
        atomicAdd(&hist[dst[base + i] >> BSHIFT], 1);
    __syncthreads();
    for (int b = t; b < 1024; b += PT) {
        int c = hist[b];
        if (c > 0) atomicAdd(&bcnt[b], c);
    }
}

// exclusive scan of bucket counts (nb <= 1024); writes boff (+boff[nb]=E) and bcur
__global__ void __launch_bounds__(1024) k_bscan(
    const int* __restrict__ bcnt, int* __restrict__ boff, int* __restrict__ bcur,
    int nb, int E)
{
    __shared__ int s[1024];
    int t = threadIdx.x;
    int v = (t < nb) ? bcnt[t] : 0;
    s[t] = v;
    __syncthreads();
    for (int off = 1; off < 1024; off <<= 1) {
        int a = (t >= off) ? s[t - off] : 0;
        __syncthreads();
        s[t] += a;
        __syncthreads();
    }
    if (t < nb) { int ex = s[t] - v; boff[t] = ex; bcur[t] = ex; }
    if (t == 0) boff[nb] = E;
}

// ---------------- phase 1: LDS multisplit into buckets ----------------
// out rec: .x = (src<<8)|(dst&255), .y = half2(eattr)
__global__ void __launch_bounds__(PT) k_part(
    const int* __restrict__ src, const int* __restrict__ dst,
    const float* __restrict__ eattr, int* __restrict__ bcur,
    uint2* __restrict__ grecs, int E)
{
    __shared__ int hist[1024], lofs[1024], gbase[1024], lcur[1024];
    __shared__ int scan_s[PT];
    __shared__ uint2 srecs[PCHUNK];
    __shared__ unsigned int gaddr[PCHUNK];
    int t = threadIdx.x;
    int base = blockIdx.x * PCHUNK;
    int cnt = E - base; if (cnt > PCHUNK) cnt = PCHUNK;

    for (int b = t; b < 1024; b += PT) hist[b] = 0;
    __syncthreads();
    for (int i = t; i < cnt; i += PT)
        atomicAdd(&hist[dst[base + i] >> BSHIFT], 1);
    __syncthreads();
    int h0 = hist[2*t], h1 = hist[2*t+1];
    int pair = h0 + h1;
    scan_s[t] = pair;
    __syncthreads();
    for (int off = 1; off < PT; off <<= 1) {
        int add = (t >= off) ? scan_s[t - off] : 0;
        __syncthreads();
        scan_s[t] += add;
        __syncthreads();
    }
    int pbase = scan_s[t] - pair;
    lofs[2*t]   = pbase;
    lofs[2*t+1] = pbase + h0;
    __syncthreads();
    for (int b = t; b < 1024; b += PT) {
        int c = hist[b];
        gbase[b] = c > 0 ? atomicAdd(&bcur[b], c) : 0;
        lcur[b] = 0;
    }
    __syncthreads();
    for (int i = t; i < cnt; i += PT) {
        int e = base + i;
        int d = dst[e];
        int b = d >> BSHIFT;
        float2 ea = ((const float2*)eattr)[e];
        __half2 hv = __floats2half2_rn(ea.x, ea.y);
        unsigned int eb = *reinterpret_cast<unsigned int*>(&hv);
        int q = atomicAdd(&lcur[b], 1);
        int idx = lofs[b] + q;
        srecs[idx] = make_uint2(((unsigned int)src[e] << 8) | (unsigned int)(d & (BNODES-1)), eb);
        gaddr[idx] = (unsigned int)(gbase[b] + q);
    }
    __syncthreads();
    for (int i = t; i < cnt; i += PT)
        grecs[gaddr[i]] = srecs[i];
}

// ---------------- phase 2: per-bucket in-LDS node sort + row emission ----------------
__global__ void __launch_bounds__(256) k_fine(
    const int* __restrict__ boff, uint2* recs, int* __restrict__ row, int N, int E)
{
    __shared__ uint2 rin[FCAP];
    __shared__ uint2 rout[FCAP];
    __shared__ int lhist[256], lsc[256], lcur2[256];
    int b = blockIdx.x;
    int bstart = boff[b], bend = boff[b+1];
    int cnt = bend - bstart;
    if (cnt > FCAP) cnt = FCAP;   // safety clamp (+14 sigma margin)
    int t = threadIdx.x;
    lhist[t] = 0;
    __syncthreads();
    for (int i = t; i < cnt; i += 256) {
        uint2 r = recs[bstart + i];
        rin[i] = r;
        atomicAdd(&lhist[r.x & (BNODES-1)], 1);
    }
    __syncthreads();
    int v = lhist[t];
    lsc[t] = v;
    __syncthreads();
    for (int off = 1; off < 256; off <<= 1) {
        int add = (t >= off) ? lsc[t - off] : 0;
        __syncthreads();
        lsc[t] += add;
        __syncthreads();
    }
    int ex = lsc[t] - v;      // exclusive in-bucket prefix
    lcur2[t] = ex;
    int n = (b << BSHIFT) + t;
    if (n < N) row[n] = bstart + ex;
    if (n == N - 1) row[N] = E;
    __syncthreads();
    for (int i = t; i < cnt; i += 256) {
        uint2 r = rin[i];
        int p = atomicAdd(&lcur2[r.x & (BNODES-1)], 1);
        rout[p] = make_uint2(r.x >> 8, r.y);
    }
    __syncthreads();
    for (int i = t; i < cnt; i += 256)
        recs[bstart + i] = rout[i];
}

// ---------------- per-(node,head) online-softmax aggregation ----------------
struct AggState { float m, s, acc[8]; };

__device__ __forceinline__ void agg_edge(
    AggState& st, const float* va, const float* xd,
    const float* w0, const float* w1, const float* at,
    float ea0, float ea1)
{
    float lg = 0.f;
#pragma unroll
    for (int o = 0; o < 8; o++) {
        float mv = va[o] + xd[o] + (w0[o]*ea0 + w1[o]*ea1);
        mv = mv > 0.f ? mv : 0.2f*mv;      // leaky_relu 0.2
        lg += mv * at[o];
    }
    float nm = fmaxf(st.m, lg);
    float sc = __expf(st.m - nm);
    float wv = __expf(lg - nm);
    st.s = st.s*sc + wv;
#pragma unroll
    for (int o = 0; o < 8; o++) st.acc[o] = st.acc[o]*sc + wv*va[o];
    st.m = nm;
}

__device__ __forceinline__ void agg_node_head(
    int n, int h,
    const int* __restrict__ row, const uint2* __restrict__ recs,
    const __half* __restrict__ xl, const float* __restrict__ xr,
    const float* __restrict__ we, const float* __restrict__ att,
    const float* __restrict__ bias, float* out)
{
    int kb = h*8;
    float xd[8], w0[8], w1[8], at[8];
    {
        const float4* xrp = (const float4*)(xr + (size_t)n*HO + kb);
        float4 d0 = xrp[0], d1 = xrp[1];
        xd[0]=d0.x; xd[1]=d0.y; xd[2]=d0.z; xd[3]=d0.w;
        xd[4]=d1.x; xd[5]=d1.y; xd[6]=d1.z; xd[7]=d1.w;
    }
#pragma unroll
    for (int o = 0; o < 8; o++) {
        w0[o] = we[2*(kb+o)];
        w1[o] = we[2*(kb+o)+1];
        at[o] = att[kb+o];
    }
    AggState st;
    st.m = -INFINITY; st.s = 0.f;
#pragma unroll
    for (int o = 0; o < 8; o++) st.acc[o] = 0.f;

    int i = row[n], end = row[n+1];
    for (; i + 4 <= end; i += 4) {
        uint2 rA = recs[i], rB = recs[i+1], rC = recs[i+2], rD = recs[i+3];
        float vA[8], vB[8], vC[8], vD[8];
        load_half8(xl + (size_t)rA.x*HO + kb, vA);
        load_half8(xl + (size_t)rB.x*HO + kb, vB);
        load_half8(xl + (size_t)rC.x*HO + kb, vC);
        load_half8(xl + (size_t)rD.x*HO + kb, vD);
        __half2 hA = *reinterpret_cast<__half2*>(&rA.y);
        __half2 hB = *reinterpret_cast<__half2*>(&rB.y);
        __half2 hC = *reinterpret_cast<__half2*>(&rC.y);
        __half2 hD = *reinterpret_cast<__half2*>(&rD.y);
        agg_edge(st, vA, xd, w0, w1, at, __low2float(hA), __high2float(hA));
        agg_edge(st, vB, xd, w0, w1, at, __low2float(hB), __high2float(hB));
        agg_edge(st, vC, xd, w0, w1, at, __low2float(hC), __high2float(hC));
        agg_edge(st, vD, xd, w0, w1, at, __low2float(hD), __high2float(hD));
    }
    for (; i < end; i++) {
        uint2 rA = recs[i];
        float vA[8];
        load_half8(xl + (size_t)rA.x*HO + kb, vA);
        __half2 hA = *reinterpret_cast<__half2*>(&rA.y);
        agg_edge(st, vA, xd, w0, w1, at, __low2float(hA), __high2float(hA));
    }
    float inv = 1.f/(st.s + 1e-16f);
#pragma unroll
    for (int o = 0; o < 8; o++) out[o] = st.acc[o]*inv + bias[kb+o];
}

// layer 1: + lrelu(0.1), write h buffer
__global__ void __launch_bounds__(256) node_agg_l1(
    const int* __restrict__ row, const uint2* __restrict__ recs,
    const __half* __restrict__ xl, const float* __restrict__ xr,
    const float* __restrict__ we, const float* __restrict__ att,
    const float* __restrict__ bias, float* __restrict__ hout, int N)
{
    int tid = blockIdx.x * 256 + threadIdx.x;
    int n = tid >> 1, h = tid & 1;
    if (n >= N) return;
    float out[8];
    agg_node_head(n, h, row, recs, xl, xr, we, att, bias, out);
    float4* hp = (float4*)(hout + (size_t)n*HO + h*8);
    hp[0] = make_float4(lrelu(out[0],0.1f), lrelu(out[1],0.1f), lrelu(out[2],0.1f), lrelu(out[3],0.1f));
    hp[1] = make_float4(lrelu(out[4],0.1f), lrelu(out[5],0.1f), lrelu(out[6],0.1f), lrelu(out[7],0.1f));
}

// transform h by layer-2 weights -> xl2(fp16), xr2(fp32)
__global__ void __launch_bounds__(256) node_transform(
    const float* __restrict__ hin,
    const float* __restrict__ wl2, const float* __restrict__ bl2,
    const float* __restrict__ wr2, const float* __restrict__ br2,
    __half* __restrict__ xl2, float* __restrict__ xr2, int N)
{
    int n = blockIdx.x * 256 + threadIdx.x;
    if (n >= N) return;
    float h[HO];
    const float4* hp = (const float4*)(hin + (size_t)n*HO);
#pragma unroll
    for (int q = 0; q < 4; q++) {
        float4 v = hp[q];
        h[4*q]=v.x; h[4*q+1]=v.y; h[4*q+2]=v.z; h[4*q+3]=v.w;
    }
    float ol[HO], orr[HO];
#pragma unroll
    for (int j = 0; j < HO; j++) {
        float a = bl2[j], b = br2[j];
#pragma unroll
        for (int k = 0; k < HO; k++) { a += wl2[HO*j+k]*h[k]; b += wr2[HO*j+k]*h[k]; }
        ol[j] = a; orr[j] = b;
    }
    store_half8(xl2 + (size_t)n*HO,     ol);
    store_half8(xl2 + (size_t)n*HO + 8, ol + 8);
    float4* xr4 = (float4*)(xr2 + (size_t)n*HO);
#pragma unroll
    for (int q = 0; q < 4; q++)
        xr4[q] = make_float4(orr[4*q], orr[4*q+1], orr[4*q+2], orr[4*q+3]);
}

// layer 2: aggregate (+bias), block-reduce, write partials column-major:
// partials[col * pstride + blockIdx]
__global__ void __launch_bounds__(256) node_agg_l2(
    const int* __restrict__ row, const uint2* __restrict__ recs,
    const __half* __restrict__ xl, const float* __restrict__ xr,
    const float* __restrict__ we, const float* __restrict__ att,
    const float* __restrict__ bias, float* __restrict__ partials, int pstride, int N)
{
    int tid = blockIdx.x * 256 + threadIdx.x;
    int n = tid >> 1, h = tid & 1;
    float out[8];
    if (n < N) {
        agg_node_head(n, h, row, recs, xl, xr, we, att, bias, out);
    } else {
#pragma unroll
        for (int o = 0; o < 8; o++) out[o] = 0.f;
    }
#pragma unroll
    for (int off = 32; off >= 2; off >>= 1) {
#pragma unroll
        for (int o = 0; o < 8; o++) out[o] += __shfl_down(out[o], off, 64);
    }
    __shared__ float sm[4][2][8];
    int wave = threadIdx.x >> 6, lane = threadIdx.x & 63;
    if (lane < 2) {
#pragma unroll
        for (int o = 0; o < 8; o++) sm[wave][lane][o] = out[o];
    }
    __syncthreads();
    if (threadIdx.x < 16) {
        int hh = threadIdx.x >> 3, oo = threadIdx.x & 7;
        float t = sm[0][hh][oo] + sm[1][hh][oo] + sm[2][hh][oo] + sm[3][hh][oo];
        partials[(size_t)(hh*8 + oo) * pstride + blockIdx.x] = t;
    }
}

// parallel partials fold: one block per column, coalesced reads
__global__ void __launch_bounds__(256) k_reduce(
    const float* __restrict__ partials, int pstride, int nparts,
    float* __restrict__ pool)
{
    __shared__ float s[256];
    int c = blockIdx.x;           // column 0..15
    int t = threadIdx.x;
    const float* col = partials + (size_t)c * pstride;
    float acc = 0.f;
    for (int r = t; r < nparts; r += 256) acc += col[r];
    s[t] = acc;
    __syncthreads();
#pragma unroll
    for (int off = 128; off > 0; off >>= 1) {
        if (t < off) s[t] += s[t + off];
        __syncthreads();
    }
    if (t == 0) pool[c] = s[0];
}

// ---------------- final tail (pool[16] precomputed) ----------------
__global__ void __launch_bounds__(64) final_mlp(
    const float* __restrict__ pool, const float* __restrict__ meta,
    const float* __restrict__ sp1_w, const float* __restrict__ sp1_b,
    const float* __restrict__ sp2_w, const float* __restrict__ sp2_b,
    const float* __restrict__ me_w, const float* __restrict__ me_b,
    const float* __restrict__ fc1_w, const float* __restrict__ fc1_b,
    const float* __restrict__ fc2_w, const float* __restrict__ fc2_b,
    const float* __restrict__ fc3_w, const float* __restrict__ fc3_b,
    float* __restrict__ out)
{
    __shared__ float s1[64], zb[24], z1[24], z2[8];
    int t = threadIdx.x;
    {
        float acc = sp1_b[t];
        for (int k = 0; k < 16; k++) acc += pool[k]*sp1_w[t*16+k];
        s1[t] = lrelu(acc, 0.1f);
    }
    __syncthreads();
    if (t < 16) {
        float acc = sp2_b[t];
        for (int k = 0; k < 64; k++) acc += s1[k]*sp2_w[t*64+k];
        zb[t] = acc;
    } else if (t < 24) {
        int j = t - 16;
        float acc = me_b[j];
        for (int k = 0; k < 6; k++) acc += meta[k]*me_w[j*6+k];
        zb[t] = lrelu(acc, 0.1f);
    }
    __syncthreads();
    if (t < 24) {
        float acc = fc1_b[t];
        for (int k = 0; k < 24; k++) acc += zb[k]*fc1_w[t*24+k];
        z1[t] = lrelu(acc, 0.1f);
    }
    __syncthreads();
    if (t < 8) {
        float acc = fc2_b[t];
        for (int k = 0; k < 24; k++) acc += z1[k]*fc2_w[t*24+k];
        z2[t] = lrelu(acc, 0.1f);
    }
    __syncthreads();
    if (t == 0) {
        float z3[3]; float mxv = -1e30f;
        for (int j = 0; j < 3; j++) {
            float acc = fc3_b[j];
            for (int k = 0; k < 8; k++) acc += z2[k]*fc3_w[j*8+k];
            z3[j] = acc; mxv = fmaxf(mxv, acc);
        }
        float s = 0.f;
        for (int j = 0; j < 3; j++) { z3[j] = __expf(z3[j]-mxv); s += z3[j]; }
        for (int j = 0; j < 3; j++) out[j] = z3[j]/s;
    }
}

extern "C" void kernel_launch(void* const* d_in, const int* in_sizes, int n_in,
                              void* d_out, int out_size, void* d_ws, size_t ws_size,
                              hipStream_t stream)
{
    const float* x      = (const float*)d_in[0];
    const int*   eidx   = (const int*)  d_in[1];
    const float* eattr  = (const float*)d_in[2];
    const float* meta   = (const float*)d_in[3];
    const float* ft1_w  = (const float*)d_in[4];
    const float* ft1_b  = (const float*)d_in[5];
    const float* ft2_w  = (const float*)d_in[6];
    const float* ft2_b  = (const float*)d_in[7];
    const float* g1_wl  = (const float*)d_in[8];
    const float* g1_bl  = (const float*)d_in[9];
    const float* g1_wr  = (const float*)d_in[10];
    const float* g1_br  = (const float*)d_in[11];
    const float* g1_we  = (const float*)d_in[12];
    const float* g1_att = (const float*)d_in[13];
    const float* g1_bias= (const float*)d_in[14];
    const float* g2_wl  = (const float*)d_in[15];
    const float* g2_bl  = (const float*)d_in[16];
    const float* g2_wr  = (const float*)d_in[17];
    const float* g2_br  = (const float*)d_in[18];
    const float* g2_we  = (const float*)d_in[19];
    const float* g2_att = (const float*)d_in[20];
    const float* g2_bias= (const float*)d_in[21];
    const float* sp1_w  = (const float*)d_in[22];
    const float* sp1_b  = (const float*)d_in[23];
    const float* sp2_w  = (const float*)d_in[24];
    const float* sp2_b  = (const float*)d_in[25];
    const float* me_w   = (const float*)d_in[26];
    const float* me_b   = (const float*)d_in[27];
    const float* fc1_w  = (const float*)d_in[28];
    const float* fc1_b  = (const float*)d_in[29];
    const float* fc2_w  = (const float*)d_in[30];
    const float* fc2_b  = (const float*)d_in[31];
    const float* fc3_w  = (const float*)d_in[32];
    const float* fc3_b  = (const float*)d_in[33];
    float* out = (float*)d_out;

    const int N = in_sizes[0] / 3;
    const int E = in_sizes[2] / 2;
    const int* src = eidx;
    const int* dst = eidx + E;

    const int BN    = (N + 255) / 256;
    const int BN2   = (2*N + 255) / 256;           // agg kernels: 2 threads/node
    const int NBUCK = (N + BNODES - 1) >> BSHIFT;  // 977 (<= 1024)
    const int BP    = (E + PCHUNK - 1) / PCHUNK;   // partition blocks
    const int pstride = (BN2 + 63) & ~63;          // column-major partials stride

    // workspace layout (256B-aligned):
    char* w = (char*)d_ws;
    size_t off = 0;
    auto take = [&](size_t bytes) { size_t o = off; off += (bytes + 255) & ~(size_t)255; return o; };
    int*    row      = (int*)   (w + take((size_t)4*(N+1)));
    int*    bcnt     = (int*)   (w + take(4096));
    int*    boff     = (int*)   (w + take(4096 + 4));
    int*    bcur     = (int*)   (w + take(4096));
    float*  pool     = (float*) (w + take(64));
    float*  partials = (float*) (w + take((size_t)4*16*pstride));
    uint2*  recs     = (uint2*) (w + take((size_t)8*E));
    __half* xl       = (__half*)(w + take((size_t)32*N));   // fp16 node table
    float*  xr       = (float*) (w + take((size_t)64*N));
    float*  hbuf     = (float*) (w + take((size_t)64*N));
    // total ~= 1MB + 40MB + 8MB + 32MB ~= 81MB

    hipMemsetAsync(bcnt, 0, 4096, stream);

    // node features + layer-1 transforms
    node_l1<<<BN, 256, 0, stream>>>(x, ft1_w, ft1_b, ft2_w, ft2_b,
                                    g1_wl, g1_bl, g1_wr, g1_br, xl, xr, N);
    // bucket histogram + scan + two-phase dst-sort (graph-only; shared by both layers)
    k_bhist<<<BP, PT, 0, stream>>>(dst, bcnt, E);
    k_bscan<<<1, 1024, 0, stream>>>(bcnt, boff, bcur, NBUCK, E);
    k_part<<<BP, PT, 0, stream>>>(src, dst, eattr, bcur, recs, E);
    k_fine<<<NBUCK, 256, 0, stream>>>(boff, recs, row, N, E);

    // ---- layer 1 ----
    node_agg_l1<<<BN2, 256, 0, stream>>>(row, recs, xl, xr,
                                         g1_we, g1_att, g1_bias, hbuf, N);
    node_transform<<<BN, 256, 0, stream>>>(hbuf, g2_wl, g2_bl, g2_wr, g2_br, xl, xr, N);
    // ---- layer 2 ----
    node_agg_l2<<<BN2, 256, 0, stream>>>(row, recs, xl, xr,
                                         g2_we, g2_att, g2_bias, partials, pstride, N);
    // ---- tail ----
    k_reduce<<<16, 256, 0, stream>>>(partials, pstride, BN2, pool);
    final_mlp<<<1, 64, 0, stream>>>(pool, meta, sp1_w, sp1_b, sp2_w, sp2_b,
                                    me_w, me_b, fc1_w, fc1_b, fc2_w, fc2_b,
                                    fc3_w, fc3_b, out);
}

// Round 10
// 468.830 us; speedup vs baseline: 5.2325x; 1.0780x over previous
//
#include <hip/hip_runtime.h>
#include <hip/hip_bf16.h>
#include <hip/hip_fp16.h>
#include <math.h>

// SportsGNN: ftMLP -> GATv2 x2 -> sumpool -> MLP -> softmax
// N=250000, E=5000000, H=2, O=8 (HO=16)
// Round-10: round-9 with the partition subsystem restructured:
//  - padded per-bucket regions (CAP2 recs) -> no pre-histogram (k_bhist/k_bscan gone)
//  - k_part: PCHUNK 6144 + ushort bid (78KB LDS -> 2 blocks/CU)
//  - k_fine: single LDS buffer (50KB -> 3 blocks/CU), emits rowS/rowE
// Agg kernels byte-identical except rowS/rowE indexing.

#define HO 16
#define BSHIFT 8
#define BNODES 256
#define PT 512          // k_part threads
#define PCHUNK 6144     // edges per partition block
#define CAP2 6016       // per-bucket record capacity (mean ~5117, +12.6 sigma)

__device__ __forceinline__ float lrelu(float x, float s) { return x > 0.f ? x : s * x; }

__device__ __forceinline__ void store_half8(__half* p, const float* v) {
    __half2 hx[4];
#pragma unroll
    for (int q = 0; q < 4; q++) hx[q] = __floats2half2_rn(v[2*q], v[2*q+1]);
    *reinterpret_cast<uint4*>(p) = *reinterpret_cast<uint4*>(hx);
}

__device__ __forceinline__ void load_half8(const __half* p, float* v) {
    uint4 u = *reinterpret_cast<const uint4*>(p);
    const __half2* h2 = reinterpret_cast<const __half2*>(&u);
#pragma unroll
    for (int q = 0; q < 4; q++) {
        float2 f = __half22float2(h2[q]);
        v[2*q] = f.x; v[2*q+1] = f.y;
    }
}

// ---------------- node kernel, layer 1: x[N,3] -> ftMLP -> xl1(fp16),xr1(fp32) ----------------
__global__ void __launch_bounds__(256) node_l1(
    const float* __restrict__ x,
    const float* __restrict__ ft1_w, const float* __restrict__ ft1_b,
    const float* __restrict__ ft2_w, const float* __restrict__ ft2_b,
    const float* __restrict__ wl, const float* __restrict__ bl,
    const float* __restrict__ wr, const float* __restrict__ br,
    __half* __restrict__ xl, float* __restrict__ xr, int N)
{
    int n = blockIdx.x * 256 + threadIdx.x;
    if (n >= N) return;
    float x0 = x[3*n], x1 = x[3*n+1], x2 = x[3*n+2];
    float h1[8];
#pragma unroll
    for (int j = 0; j < 8; j++) {
        float a = ft1_w[3*j]*x0 + ft1_w[3*j+1]*x1 + ft1_w[3*j+2]*x2 + ft1_b[j];
        h1[j] = lrelu(a, 0.1f);
    }
    float h2[8];
#pragma unroll
    for (int j = 0; j < 8; j++) {
        float a = ft2_b[j];
#pragma unroll
        for (int k = 0; k < 8; k++) a += ft2_w[8*j+k]*h1[k];
        h2[j] = lrelu(a, 0.1f);
    }
    float ol[HO], orr[HO];
#pragma unroll
    for (int j = 0; j < HO; j++) {
        float a = bl[j], b = br[j];
#pragma unroll
        for (int k = 0; k < 8; k++) { a += wl[8*j+k]*h2[k]; b += wr[8*j+k]*h2[k]; }
        ol[j] = a; orr[j] = b;
    }
    store_half8(xl + (size_t)n*HO,     ol);
    store_half8(xl + (size_t)n*HO + 8, ol + 8);
    float4* xr4 = (float4*)(xr + (size_t)n*HO);
#pragma unroll
    for (int q = 0; q < 4; q++)
        xr4[q] = make_float4(orr[4*q], orr[4*q+1], orr[4*q+2], orr[4*q+3]);
}

// bucket cursors: bcur[b] = b*CAP2 (start of each padded region)
__global__ void __launch_bounds__(256) k_binit(int* __restrict__ bcur)
{
    int b = blockIdx.x * 256 + threadIdx.x;
    if (b < 1024) bcur[b] = b * CAP2;
}

// ---------------- phase 1: LDS multisplit into padded bucket regions ----------------
// out rec: .x = (src<<8)|(dst&255), .y = half2(eattr)
__global__ void __launch_bounds__(PT) k_part(
    const int* __restrict__ src, const int* __restrict__ dst,
    const float* __restrict__ eattr, int* __restrict__ bcur,
    uint2* __restrict__ grecs, int E)
{
    __shared__ int hist[1024], lofs[1024], gofs[1024], lcur[1024];
    __shared__ int scan_s[PT];
    __shared__ uint2 srecs[PCHUNK];
    __shared__ unsigned short bid[PCHUNK];
    int t = threadIdx.x;
    int base = blockIdx.x * PCHUNK;
    int cnt = E - base; if (cnt > PCHUNK) cnt = PCHUNK;

    for (int b = t; b < 1024; b += PT) hist[b] = 0;
    __syncthreads();
    // stage A: bucket histogram (dst-only read)
    for (int i = t; i < cnt; i += PT)
        atomicAdd(&hist[dst[base + i] >> BSHIFT], 1);
    __syncthreads();
    // scan 1024 entries with 512 threads (pair-sum Hillis-Steele)
    int h0 = hist[2*t], h1 = hist[2*t+1];
    int pair = h0 + h1;
    scan_s[t] = pair;
    __syncthreads();
    for (int off = 1; off < PT; off <<= 1) {
        int add = (t >= off) ? scan_s[t - off] : 0;
        __syncthreads();
        scan_s[t] += add;
        __syncthreads();
    }
    int pbase = scan_s[t] - pair;
    lofs[2*t]   = pbase;
    lofs[2*t+1] = pbase + h0;
    __syncthreads();
    // claim global runs (one atomic per non-empty (block,bucket))
    for (int b = t; b < 1024; b += PT) {
        int c = hist[b];
        int g = (c > 0) ? atomicAdd(&bcur[b], c) : 0;
        gofs[b] = g - lofs[b];
        lcur[b] = 0;
    }
    __syncthreads();
    // stage B: read edges, place into LDS bucket-sorted order, remember bucket id
    for (int i = t; i < cnt; i += PT) {
        int e = base + i;
        int d = dst[e];
        int b = d >> BSHIFT;
        float2 ea = ((const float2*)eattr)[e];
        __half2 hv = __floats2half2_rn(ea.x, ea.y);
        unsigned int eb = *reinterpret_cast<unsigned int*>(&hv);
        int q = atomicAdd(&lcur[b], 1);
        int idx = lofs[b] + q;
        srecs[idx] = make_uint2(((unsigned int)src[e] << 8) | (unsigned int)(d & (BNODES-1)), eb);
        bid[idx] = (unsigned short)b;
    }
    __syncthreads();
    // stage C: write out (bucket-run coalesced); guard against region overflow
    for (int i = t; i < cnt; i += PT) {
        int b = bid[i];
        int pos = gofs[b] + i;
        if (pos < (b + 1) * CAP2) grecs[pos] = srecs[i];
    }
}

// ---------------- phase 2: per-bucket in-LDS node sort + rowS/rowE emission ----------------
// in rec: .x=(src<<8)|dlow ; out rec: .x=src, .y=half2(eattr), node-sorted, in place
__global__ void __launch_bounds__(256) k_fine(
    const int* __restrict__ bcur, uint2* recs,
    int* __restrict__ rowS, int* __restrict__ rowE, int N)
{
    __shared__ uint2 rout[CAP2];
    __shared__ int lhist[256], lsc[256], lcur2[256];
    int b = blockIdx.x;
    int bstart = b * CAP2;
    int cnt = bcur[b] - bstart;
    if (cnt > CAP2) cnt = CAP2;
    if (cnt < 0) cnt = 0;
    int t = threadIdx.x;
    lhist[t] = 0;
    __syncthreads();
    for (int i = t; i < cnt; i += 256)
        atomicAdd(&lhist[recs[bstart + i].x & (BNODES-1)], 1);
    __syncthreads();
    int v = lhist[t];
    lsc[t] = v;
    __syncthreads();
    for (int off = 1; off < 256; off <<= 1) {
        int add = (t >= off) ? lsc[t - off] : 0;
        __syncthreads();
        lsc[t] += add;
        __syncthreads();
    }
    int ex = lsc[t] - v;      // exclusive in-bucket prefix
    lcur2[t] = ex;
    int n = (b << BSHIFT) + t;
    if (n < N) { rowS[n] = bstart + ex; rowE[n] = bstart + ex + v; }
    __syncthreads();
    for (int i = t; i < cnt; i += 256) {
        uint2 r = recs[bstart + i];
        int p = atomicAdd(&lcur2[r.x & (BNODES-1)], 1);
        rout[p] = make_uint2(r.x >> 8, r.y);
    }
    __syncthreads();
    for (int i = t; i < cnt; i += 256)
        recs[bstart + i] = rout[i];
}

// ---------------- per-(node,head) online-softmax aggregation ----------------
struct AggState { float m, s, acc[8]; };

__device__ __forceinline__ void agg_edge(
    AggState& st, const float* va, const float* xd,
    const float* w0, const float* w1, const float* at,
    float ea0, float ea1)
{
    float lg = 0.f;
#pragma unroll
    for (int o = 0; o < 8; o++) {
        float mv = va[o] + xd[o] + (w0[o]*ea0 + w1[o]*ea1);
        mv = mv > 0.f ? mv : 0.2f*mv;      // leaky_relu 0.2
        lg += mv * at[o];
    }
    float nm = fmaxf(st.m, lg);
    float sc = __expf(st.m - nm);
    float wv = __expf(lg - nm);
    st.s = st.s*sc + wv;
#pragma unroll
    for (int o = 0; o < 8; o++) st.acc[o] = st.acc[o]*sc + wv*va[o];
    st.m = nm;
}

__device__ __forceinline__ void agg_node_head(
    int n, int h,
    const int* __restrict__ rowS, const int* __restrict__ rowE,
    const uint2* __restrict__ recs,
    const __half* __restrict__ xl, const float* __restrict__ xr,
    const float* __restrict__ we, const float* __restrict__ att,
    const float* __restrict__ bias, float* out)
{
    int kb = h*8;
    float xd[8], w0[8], w1[8], at[8];
    {
        const float4* xrp = (const float4*)(xr + (size_t)n*HO + kb);
        float4 d0 = xrp[0], d1 = xrp[1];
        xd[0]=d0.x; xd[1]=d0.y; xd[2]=d0.z; xd[3]=d0.w;
        xd[4]=d1.x; xd[5]=d1.y; xd[6]=d1.z; xd[7]=d1.w;
    }
#pragma unroll
    for (int o = 0; o < 8; o++) {
        w0[o] = we[2*(kb+o)];
        w1[o] = we[2*(kb+o)+1];
        at[o] = att[kb+o];
    }
    AggState st;
    st.m = -INFINITY; st.s = 0.f;
#pragma unroll
    for (int o = 0; o < 8; o++) st.acc[o] = 0.f;

    int i = rowS[n], end = rowE[n];
    for (; i + 4 <= end; i += 4) {
        uint2 rA = recs[i], rB = recs[i+1], rC = recs[i+2], rD = recs[i+3];
        float vA[8], vB[8], vC[8], vD[8];
        load_half8(xl + (size_t)rA.x*HO + kb, vA);
        load_half8(xl + (size_t)rB.x*HO + kb, vB);
        load_half8(xl + (size_t)rC.x*HO + kb, vC);
        load_half8(xl + (size_t)rD.x*HO + kb, vD);
        __half2 hA = *reinterpret_cast<__half2*>(&rA.y);
        __half2 hB = *reinterpret_cast<__half2*>(&rB.y);
        __half2 hC = *reinterpret_cast<__half2*>(&rC.y);
        __half2 hD = *reinterpret_cast<__half2*>(&rD.y);
        agg_edge(st, vA, xd, w0, w1, at, __low2float(hA), __high2float(hA));
        agg_edge(st, vB, xd, w0, w1, at, __low2float(hB), __high2float(hB));
        agg_edge(st, vC, xd, w0, w1, at, __low2float(hC), __high2float(hC));
        agg_edge(st, vD, xd, w0, w1, at, __low2float(hD), __high2float(hD));
    }
    for (; i < end; i++) {
        uint2 rA = recs[i];
        float vA[8];
        load_half8(xl + (size_t)rA.x*HO + kb, vA);
        __half2 hA = *reinterpret_cast<__half2*>(&rA.y);
        agg_edge(st, vA, xd, w0, w1, at, __low2float(hA), __high2float(hA));
    }
    float inv = 1.f/(st.s + 1e-16f);
#pragma unroll
    for (int o = 0; o < 8; o++) out[o] = st.acc[o]*inv + bias[kb+o];
}

// layer 1: + lrelu(0.1), write h buffer
__global__ void __launch_bounds__(256) node_agg_l1(
    const int* __restrict__ rowS, const int* __restrict__ rowE,
    const uint2* __restrict__ recs,
    const __half* __restrict__ xl, const float* __restrict__ xr,
    const float* __restrict__ we, const float* __restrict__ att,
    const float* __restrict__ bias, float* __restrict__ hout, int N)
{
    int tid = blockIdx.x * 256 + threadIdx.x;
    int n = tid >> 1, h = tid & 1;
    if (n >= N) return;
    float out[8];
    agg_node_head(n, h, rowS, rowE, recs, xl, xr, we, att, bias, out);
    float4* hp = (float4*)(hout + (size_t)n*HO + h*8);
    hp[0] = make_float4(lrelu(out[0],0.1f), lrelu(out[1],0.1f), lrelu(out[2],0.1f), lrelu(out[3],0.1f));
    hp[1] = make_float4(lrelu(out[4],0.1f), lrelu(out[5],0.1f), lrelu(out[6],0.1f), lrelu(out[7],0.1f));
}

// transform h by layer-2 weights -> xl2(fp16), xr2(fp32)
__global__ void __launch_bounds__(256) node_transform(
    const float* __restrict__ hin,
    const float* __restrict__ wl2, const float* __restrict__ bl2,
    const float* __restrict__ wr2, const float* __restrict__ br2,
    __half* __restrict__ xl2, float* __restrict__ xr2, int N)
{
    int n = blockIdx.x * 256 + threadIdx.x;
    if (n >= N) return;
    float h[HO];
    const float4* hp = (const float4*)(hin + (size_t)n*HO);
#pragma unroll
    for (int q = 0; q < 4; q++) {
        float4 v = hp[q];
        h[4*q]=v.x; h[4*q+1]=v.y; h[4*q+2]=v.z; h[4*q+3]=v.w;
    }
    float ol[HO], orr[HO];
#pragma unroll
    for (int j = 0; j < HO; j++) {
        float a = bl2[j], b = br2[j];
#pragma unroll
        for (int k = 0; k < HO; k++) { a += wl2[HO*j+k]*h[k]; b += wr2[HO*j+k]*h[k]; }
        ol[j] = a; orr[j] = b;
    }
    store_half8(xl2 + (size_t)n*HO,     ol);
    store_half8(xl2 + (size_t)n*HO + 8, ol + 8);
    float4* xr4 = (float4*)(xr2 + (size_t)n*HO);
#pragma unroll
    for (int q = 0; q < 4; q++)
        xr4[q] = make_float4(orr[4*q], orr[4*q+1], orr[4*q+2], orr[4*q+3]);
}

// layer 2: aggregate (+bias), block-reduce, write partials column-major
__global__ void __launch_bounds__(256) node_agg_l2(
    const int* __restrict__ rowS, const int* __restrict__ rowE,
    const uint2* __restrict__ recs,
    const __half* __restrict__ xl, const float* __restrict__ xr,
    const float* __restrict__ we, const float* __restrict__ att,
    const float* __restrict__ bias, float* __restrict__ partials, int pstride, int N)
{
    int tid = blockIdx.x * 256 + threadIdx.x;
    int n = tid >> 1, h = tid & 1;
    float out[8];
    if (n < N) {
        agg_node_head(n, h, rowS, rowE, recs, xl, xr, we, att, bias, out);
    } else {
#pragma unroll
        for (int o = 0; o < 8; o++) out[o] = 0.f;
    }
#pragma unroll
    for (int off = 32; off >= 2; off >>= 1) {
#pragma unroll
        for (int o = 0; o < 8; o++) out[o] += __shfl_down(out[o], off, 64);
    }
    __shared__ float sm[4][2][8];
    int wave = threadIdx.x >> 6, lane = threadIdx.x & 63;
    if (lane < 2) {
#pragma unroll
        for (int o = 0; o < 8; o++) sm[wave][lane][o] = out[o];
    }
    __syncthreads();
    if (threadIdx.x < 16) {
        int hh = threadIdx.x >> 3, oo = threadIdx.x & 7;
        float t = sm[0][hh][oo] + sm[1][hh][oo] + sm[2][hh][oo] + sm[3][hh][oo];
        partials[(size_t)(hh*8 + oo) * pstride + blockIdx.x] = t;
    }
}

// parallel partials fold: one block per column, coalesced reads
__global__ void __launch_bounds__(256) k_reduce(
    const float* __restrict__ partials, int pstride, int nparts,
    float* __restrict__ pool)
{
    __shared__ float s[256];
    int c = blockIdx.x;           // column 0..15
    int t = threadIdx.x;
    const float* col = partials + (size_t)c * pstride;
    float acc = 0.f;
    for (int r = t; r < nparts; r += 256) acc += col[r];
    s[t] = acc;
    __syncthreads();
#pragma unroll
    for (int off = 128; off > 0; off >>= 1) {
        if (t < off) s[t] += s[t + off];
        __syncthreads();
    }
    if (t == 0) pool[c] = s[0];
}

// ---------------- final tail (pool[16] precomputed) ----------------
__global__ void __launch_bounds__(64) final_mlp(
    const float* __restrict__ pool, const float* __restrict__ meta,
    const float* __restrict__ sp1_w, const float* __restrict__ sp1_b,
    const float* __restrict__ sp2_w, const float* __restrict__ sp2_b,
    const float* __restrict__ me_w, const float* __restrict__ me_b,
    const float* __restrict__ fc1_w, const float* __restrict__ fc1_b,
    const float* __restrict__ fc2_w, const float* __restrict__ fc2_b,
    const float* __restrict__ fc3_w, const float* __restrict__ fc3_b,
    float* __restrict__ out)
{
    __shared__ float s1[64], zb[24], z1[24], z2[8];
    int t = threadIdx.x;
    {
        float acc = sp1_b[t];
        for (int k = 0; k < 16; k++) acc += pool[k]*sp1_w[t*16+k];
        s1[t] = lrelu(acc, 0.1f);
    }
    __syncthreads();
    if (t < 16) {
        float acc = sp2_b[t];
        for (int k = 0; k < 64; k++) acc += s1[k]*sp2_w[t*64+k];
        zb[t] = acc;
    } else if (t < 24) {
        int j = t - 16;
        float acc = me_b[j];
        for (int k = 0; k < 6; k++) acc += meta[k]*me_w[j*6+k];
        zb[t] = lrelu(acc, 0.1f);
    }
    __syncthreads();
    if (t < 24) {
        float acc = fc1_b[t];
        for (int k = 0; k < 24; k++) acc += zb[k]*fc1_w[t*24+k];
        z1[t] = lrelu(acc, 0.1f);
    }
    __syncthreads();
    if (t < 8) {
        float acc = fc2_b[t];
        for (int k = 0; k < 24; k++) acc += z1[k]*fc2_w[t*24+k];
        z2[t] = lrelu(acc, 0.1f);
    }
    __syncthreads();
    if (t == 0) {
        float z3[3]; float mxv = -1e30f;
        for (int j = 0; j < 3; j++) {
            float acc = fc3_b[j];
            for (int k = 0; k < 8; k++) acc += z2[k]*fc3_w[j*8+k];
            z3[j] = acc; mxv = fmaxf(mxv, acc);
        }
        float s = 0.f;
        for (int j = 0; j < 3; j++) { z3[j] = __expf(z3[j]-mxv); s += z3[j]; }
        for (int j = 0; j < 3; j++) out[j] = z3[j]/s;
    }
}

extern "C" void kernel_launch(void* const* d_in, const int* in_sizes, int n_in,
                              void* d_out, int out_size, void* d_ws, size_t ws_size,
                              hipStream_t stream)
{
    const float* x      = (const float*)d_in[0];
    const int*   eidx   = (const int*)  d_in[1];
    const float* eattr  = (const float*)d_in[2];
    const float* meta   = (const float*)d_in[3];
    const float* ft1_w  = (const float*)d_in[4];
    const float* ft1_b  = (const float*)d_in[5];
    const float* ft2_w  = (const float*)d_in[6];
    const float* ft2_b  = (const float*)d_in[7];
    const float* g1_wl  = (const float*)d_in[8];
    const float* g1_bl  = (const float*)d_in[9];
    const float* g1_wr  = (const float*)d_in[10];
    const float* g1_br  = (const float*)d_in[11];
    const float* g1_we  = (const float*)d_in[12];
    const float* g1_att = (const float*)d_in[13];
    const float* g1_bias= (const float*)d_in[14];
    const float* g2_wl  = (const float*)d_in[15];
    const float* g2_bl  = (const float*)d_in[16];
    const float* g2_wr  = (const float*)d_in[17];
    const float* g2_br  = (const float*)d_in[18];
    const float* g2_we  = (const float*)d_in[19];
    const float* g2_att = (const float*)d_in[20];
    const float* g2_bias= (const float*)d_in[21];
    const float* sp1_w  = (const float*)d_in[22];
    const float* sp1_b  = (const float*)d_in[23];
    const float* sp2_w  = (const float*)d_in[24];
    const float* sp2_b  = (const float*)d_in[25];
    const float* me_w   = (const float*)d_in[26];
    const float* me_b   = (const float*)d_in[27];
    const float* fc1_w  = (const float*)d_in[28];
    const float* fc1_b  = (const float*)d_in[29];
    const float* fc2_w  = (const float*)d_in[30];
    const float* fc2_b  = (const float*)d_in[31];
    const float* fc3_w  = (const float*)d_in[32];
    const float* fc3_b  = (const float*)d_in[33];
    float* out = (float*)d_out;

    const int N = in_sizes[0] / 3;
    const int E = in_sizes[2] / 2;
    const int* src = eidx;
    const int* dst = eidx + E;

    const int BN    = (N + 255) / 256;
    const int BN2   = (2*N + 255) / 256;           // agg kernels: 2 threads/node
    const int NBUCK = (N + BNODES - 1) >> BSHIFT;  // 977 (<= 1024)
    const int BP    = (E + PCHUNK - 1) / PCHUNK;   // partition blocks
    const int pstride = (BN2 + 63) & ~63;          // column-major partials stride

    // workspace layout (256B-aligned):
    char* w = (char*)d_ws;
    size_t off = 0;
    auto take = [&](size_t bytes) { size_t o = off; off += (bytes + 255) & ~(size_t)255; return o; };
    int*    rowS     = (int*)   (w + take((size_t)4*N));
    int*    rowE     = (int*)   (w + take((size_t)4*N));
    int*    bcur     = (int*)   (w + take(4096));
    float*  pool     = (float*) (w + take(64));
    float*  partials = (float*) (w + take((size_t)4*16*pstride));
    uint2*  recs     = (uint2*) (w + take((size_t)8*NBUCK*CAP2));  // padded regions
    __half* xl       = (__half*)(w + take((size_t)32*N));          // fp16 node table
    float*  xr       = (float*) (w + take((size_t)64*N));
    float*  hbuf     = (float*) (w + take((size_t)64*N));
    // total ~= 2MB + 45MB + 8MB + 16MB + 16MB ~= 87MB

    // node features + layer-1 transforms
    node_l1<<<BN, 256, 0, stream>>>(x, ft1_w, ft1_b, ft2_w, ft2_b,
                                    g1_wl, g1_bl, g1_wr, g1_br, xl, xr, N);
    // two-phase dst-sort into padded bucket regions (graph-only; shared by both layers)
    k_binit<<<4, 256, 0, stream>>>(bcur);
    k_part<<<BP, PT, 0, stream>>>(src, dst, eattr, bcur, recs, E);
    k_fine<<<NBUCK, 256, 0, stream>>>(bcur, recs, rowS, rowE, N);

    // ---- layer 1 ----
    node_agg_l1<<<BN2, 256, 0, stream>>>(rowS, rowE, recs, xl, xr,
                                         g1_we, g1_att, g1_bias, hbuf, N);
    node_transform<<<BN, 256, 0, stream>>>(hbuf, g2_wl, g2_bl, g2_wr, g2_br, xl, xr, N);
    // ---- layer 2 ----
    node_agg_l2<<<BN2, 256, 0, stream>>>(rowS, rowE, recs, xl, xr,
                                         g2_we, g2_att, g2_bias, partials, pstride, N);
    // ---- tail ----
    k_reduce<<<16, 256, 0, stream>>>(partials, pstride, BN2, pool);
    final_mlp<<<1, 64, 0, stream>>>(pool, meta, sp1_w, sp1_b, sp2_w, sp2_b,
                                    me_w, me_b, fc1_w, fc1_b, fc2_w, fc2_b,
                                    fc3_w, fc3_b, out);
}

// Round 11
// 420.901 us; speedup vs baseline: 5.8284x; 1.1139x over previous
//
#include <hip/hip_runtime.h>
#include <hip/hip_bf16.h>
#include <hip/hip_fp16.h>
#include <math.h>

// SportsGNN: ftMLP -> GATv2 x2 -> sumpool -> MLP -> softmax
// N=250000, E=5000000, H=2, O=8 (HO=16)
// Round-11: round-10 skeleton with
//  - xl gather table in fp8 e4m3 (4 MB -> fits per-XCD L2; HW cvt_pk builtins)
//  - node_transform fused into node_agg_l1 (lane-pair shfl_xor exchange);
//    xr updated in place, xl ping-pongs A->B. hbuf deleted.

#define HO 16
#define BSHIFT 8
#define BNODES 256
#define PT 512          // k_part threads
#define PCHUNK 6144     // edges per partition block
#define CAP2 6016       // per-bucket record capacity (mean ~5117, +12.6 sigma)

typedef __attribute__((ext_vector_type(2))) float v2f;

__device__ __forceinline__ float lrelu(float x, float s) { return x > 0.f ? x : s * x; }

// pack 8 floats -> 8 fp8 bytes (e4m3 HW rounding)
__device__ __forceinline__ uint2 pack_fp8x8(const float* v) {
    int a = __builtin_amdgcn_cvt_pk_fp8_f32(v[0], v[1], 0, false);
    a     = __builtin_amdgcn_cvt_pk_fp8_f32(v[2], v[3], a, true);
    int b = __builtin_amdgcn_cvt_pk_fp8_f32(v[4], v[5], 0, false);
    b     = __builtin_amdgcn_cvt_pk_fp8_f32(v[6], v[7], b, true);
    return make_uint2((unsigned int)a, (unsigned int)b);
}

// unpack 8 fp8 bytes -> 8 floats
__device__ __forceinline__ void unpack_fp8x8(uint2 u, float* v) {
    v2f f0 = __builtin_amdgcn_cvt_pk_f32_fp8((int)u.x, false);
    v2f f1 = __builtin_amdgcn_cvt_pk_f32_fp8((int)u.x, true);
    v2f f2 = __builtin_amdgcn_cvt_pk_f32_fp8((int)u.y, false);
    v2f f3 = __builtin_amdgcn_cvt_pk_f32_fp8((int)u.y, true);
    v[0]=f0.x; v[1]=f0.y; v[2]=f1.x; v[3]=f1.y;
    v[4]=f2.x; v[5]=f2.y; v[6]=f3.x; v[7]=f3.y;
}

// ---------------- node kernel, layer 1: x[N,3] -> ftMLP -> xlA(fp8), xr(fp32) ----------------
__global__ void __launch_bounds__(256) node_l1(
    const float* __restrict__ x,
    const float* __restrict__ ft1_w, const float* __restrict__ ft1_b,
    const float* __restrict__ ft2_w, const float* __restrict__ ft2_b,
    const float* __restrict__ wl, const float* __restrict__ bl,
    const float* __restrict__ wr, const float* __restrict__ br,
    uint2* __restrict__ xlA, float* __restrict__ xr, int N)
{
    int n = blockIdx.x * 256 + threadIdx.x;
    if (n >= N) return;
    float x0 = x[3*n], x1 = x[3*n+1], x2 = x[3*n+2];
    float h1[8];
#pragma unroll
    for (int j = 0; j < 8; j++) {
        float a = ft1_w[3*j]*x0 + ft1_w[3*j+1]*x1 + ft1_w[3*j+2]*x2 + ft1_b[j];
        h1[j] = lrelu(a, 0.1f);
    }
    float h2[8];
#pragma unroll
    for (int j = 0; j < 8; j++) {
        float a = ft2_b[j];
#pragma unroll
        for (int k = 0; k < 8; k++) a += ft2_w[8*j+k]*h1[k];
        h2[j] = lrelu(a, 0.1f);
    }
    float ol[HO], orr[HO];
#pragma unroll
    for (int j = 0; j < HO; j++) {
        float a = bl[j], b = br[j];
#pragma unroll
        for (int k = 0; k < 8; k++) { a += wl[8*j+k]*h2[k]; b += wr[8*j+k]*h2[k]; }
        ol[j] = a; orr[j] = b;
    }
    uint2 p0 = pack_fp8x8(ol);
    uint2 p1 = pack_fp8x8(ol + 8);
    ((uint4*)xlA)[n] = make_uint4(p0.x, p0.y, p1.x, p1.y);
    float4* xr4 = (float4*)(xr + (size_t)n*HO);
#pragma unroll
    for (int q = 0; q < 4; q++)
        xr4[q] = make_float4(orr[4*q], orr[4*q+1], orr[4*q+2], orr[4*q+3]);
}

// bucket cursors: bcur[b] = b*CAP2 (start of each padded region)
__global__ void __launch_bounds__(256) k_binit(int* __restrict__ bcur)
{
    int b = blockIdx.x * 256 + threadIdx.x;
    if (b < 1024) bcur[b] = b * CAP2;
}

// ---------------- phase 1: LDS multisplit into padded bucket regions ----------------
// out rec: .x = (src<<8)|(dst&255), .y = half2(eattr)
__global__ void __launch_bounds__(PT) k_part(
    const int* __restrict__ src, const int* __restrict__ dst,
    const float* __restrict__ eattr, int* __restrict__ bcur,
    uint2* __restrict__ grecs, int E)
{
    __shared__ int hist[1024], lofs[1024], gofs[1024], lcur[1024];
    __shared__ int scan_s[PT];
    __shared__ uint2 srecs[PCHUNK];
    __shared__ unsigned short bid[PCHUNK];
    int t = threadIdx.x;
    int base = blockIdx.x * PCHUNK;
    int cnt = E - base; if (cnt > PCHUNK) cnt = PCHUNK;

    for (int b = t; b < 1024; b += PT) hist[b] = 0;
    __syncthreads();
    for (int i = t; i < cnt; i += PT)
        atomicAdd(&hist[dst[base + i] >> BSHIFT], 1);
    __syncthreads();
    int h0 = hist[2*t], h1 = hist[2*t+1];
    int pair = h0 + h1;
    scan_s[t] = pair;
    __syncthreads();
    for (int off = 1; off < PT; off <<= 1) {
        int add = (t >= off) ? scan_s[t - off] : 0;
        __syncthreads();
        scan_s[t] += add;
        __syncthreads();
    }
    int pbase = scan_s[t] - pair;
    lofs[2*t]   = pbase;
    lofs[2*t+1] = pbase + h0;
    __syncthreads();
    for (int b = t; b < 1024; b += PT) {
        int c = hist[b];
        int g = (c > 0) ? atomicAdd(&bcur[b], c) : 0;
        gofs[b] = g - lofs[b];
        lcur[b] = 0;
    }
    __syncthreads();
    for (int i = t; i < cnt; i += PT) {
        int e = base + i;
        int d = dst[e];
        int b = d >> BSHIFT;
        float2 ea = ((const float2*)eattr)[e];
        __half2 hv = __floats2half2_rn(ea.x, ea.y);
        unsigned int eb = *reinterpret_cast<unsigned int*>(&hv);
        int q = atomicAdd(&lcur[b], 1);
        int idx = lofs[b] + q;
        srecs[idx] = make_uint2(((unsigned int)src[e] << 8) | (unsigned int)(d & (BNODES-1)), eb);
        bid[idx] = (unsigned short)b;
    }
    __syncthreads();
    for (int i = t; i < cnt; i += PT) {
        int b = bid[i];
        int pos = gofs[b] + i;
        if (pos < (b + 1) * CAP2) grecs[pos] = srecs[i];
    }
}

// ---------------- phase 2: per-bucket in-LDS node sort + rowS/rowE emission ----------------
__global__ void __launch_bounds__(256) k_fine(
    const int* __restrict__ bcur, uint2* recs,
    int* __restrict__ rowS, int* __restrict__ rowE, int N)
{
    __shared__ uint2 rout[CAP2];
    __shared__ int lhist[256], lsc[256], lcur2[256];
    int b = blockIdx.x;
    int bstart = b * CAP2;
    int cnt = bcur[b] - bstart;
    if (cnt > CAP2) cnt = CAP2;
    if (cnt < 0) cnt = 0;
    int t = threadIdx.x;
    lhist[t] = 0;
    __syncthreads();
    for (int i = t; i < cnt; i += 256)
        atomicAdd(&lhist[recs[bstart + i].x & (BNODES-1)], 1);
    __syncthreads();
    int v = lhist[t];
    lsc[t] = v;
    __syncthreads();
    for (int off = 1; off < 256; off <<= 1) {
        int add = (t >= off) ? lsc[t - off] : 0;
        __syncthreads();
        lsc[t] += add;
        __syncthreads();
    }
    int ex = lsc[t] - v;      // exclusive in-bucket prefix
    lcur2[t] = ex;
    int n = (b << BSHIFT) + t;
    if (n < N) { rowS[n] = bstart + ex; rowE[n] = bstart + ex + v; }
    __syncthreads();
    for (int i = t; i < cnt; i += 256) {
        uint2 r = recs[bstart + i];
        int p = atomicAdd(&lcur2[r.x & (BNODES-1)], 1);
        rout[p] = make_uint2(r.x >> 8, r.y);
    }
    __syncthreads();
    for (int i = t; i < cnt; i += 256)
        recs[bstart + i] = rout[i];
}

// ---------------- per-(node,head) online-softmax aggregation ----------------
struct AggState { float m, s, acc[8]; };

__device__ __forceinline__ void agg_edge(
    AggState& st, const float* va, const float* xd,
    const float* w0, const float* w1, const float* at,
    float ea0, float ea1)
{
    float lg = 0.f;
#pragma unroll
    for (int o = 0; o < 8; o++) {
        float mv = va[o] + xd[o] + (w0[o]*ea0 + w1[o]*ea1);
        mv = mv > 0.f ? mv : 0.2f*mv;      // leaky_relu 0.2
        lg += mv * at[o];
    }
    float nm = fmaxf(st.m, lg);
    float sc = __expf(st.m - nm);
    float wv = __expf(lg - nm);
    st.s = st.s*sc + wv;
#pragma unroll
    for (int o = 0; o < 8; o++) st.acc[o] = st.acc[o]*sc + wv*va[o];
    st.m = nm;
}

// xl8: fp8 table, 2 uint2 per node (one per head). Gathers are 8B per lane.
__device__ __forceinline__ void agg_node_head(
    int n, int h,
    const int* __restrict__ rowS, const int* __restrict__ rowE,
    const uint2* __restrict__ recs,
    const uint2* __restrict__ xl8, const float* __restrict__ xr,
    const float* __restrict__ we, const float* __restrict__ att,
    const float* __restrict__ bias, float* out)
{
    int kb = h*8;
    float xd[8], w0[8], w1[8], at[8];
    {
        const float4* xrp = (const float4*)(xr + (size_t)n*HO + kb);
        float4 d0 = xrp[0], d1 = xrp[1];
        xd[0]=d0.x; xd[1]=d0.y; xd[2]=d0.z; xd[3]=d0.w;
        xd[4]=d1.x; xd[5]=d1.y; xd[6]=d1.z; xd[7]=d1.w;
    }
#pragma unroll
    for (int o = 0; o < 8; o++) {
        w0[o] = we[2*(kb+o)];
        w1[o] = we[2*(kb+o)+1];
        at[o] = att[kb+o];
    }
    AggState st;
    st.m = -INFINITY; st.s = 0.f;
#pragma unroll
    for (int o = 0; o < 8; o++) st.acc[o] = 0.f;

    int i = rowS[n], end = rowE[n];
    for (; i + 4 <= end; i += 4) {
        uint2 rA = recs[i], rB = recs[i+1], rC = recs[i+2], rD = recs[i+3];
        uint2 gA = xl8[(size_t)rA.x*2 + h];
        uint2 gB = xl8[(size_t)rB.x*2 + h];
        uint2 gC = xl8[(size_t)rC.x*2 + h];
        uint2 gD = xl8[(size_t)rD.x*2 + h];
        float vA[8], vB[8], vC[8], vD[8];
        unpack_fp8x8(gA, vA); unpack_fp8x8(gB, vB);
        unpack_fp8x8(gC, vC); unpack_fp8x8(gD, vD);
        __half2 hA = *reinterpret_cast<__half2*>(&rA.y);
        __half2 hB = *reinterpret_cast<__half2*>(&rB.y);
        __half2 hC = *reinterpret_cast<__half2*>(&rC.y);
        __half2 hD = *reinterpret_cast<__half2*>(&rD.y);
        agg_edge(st, vA, xd, w0, w1, at, __low2float(hA), __high2float(hA));
        agg_edge(st, vB, xd, w0, w1, at, __low2float(hB), __high2float(hB));
        agg_edge(st, vC, xd, w0, w1, at, __low2float(hC), __high2float(hC));
        agg_edge(st, vD, xd, w0, w1, at, __low2float(hD), __high2float(hD));
    }
    for (; i < end; i++) {
        uint2 rA = recs[i];
        uint2 gA = xl8[(size_t)rA.x*2 + h];
        float vA[8];
        unpack_fp8x8(gA, vA);
        __half2 hA = *reinterpret_cast<__half2*>(&rA.y);
        agg_edge(st, vA, xd, w0, w1, at, __low2float(hA), __high2float(hA));
    }
    float inv = 1.f/(st.s + 1e-16f);
#pragma unroll
    for (int o = 0; o < 8; o++) out[o] = st.acc[o]*inv + bias[kb+o];
}

// layer 1 fused: aggregate + lrelu(0.1) + layer-2 transform -> xlB(fp8), xr(in place)
__global__ void __launch_bounds__(256) node_agg_l1(
    const int* __restrict__ rowS, const int* __restrict__ rowE,
    const uint2* __restrict__ recs,
    const uint2* __restrict__ xlA, float* xr,
    const float* __restrict__ we, const float* __restrict__ att,
    const float* __restrict__ bias,
    const float* __restrict__ wl2, const float* __restrict__ bl2,
    const float* __restrict__ wr2, const float* __restrict__ br2,
    uint2* __restrict__ xlB, int N)
{
    int tid = blockIdx.x * 256 + threadIdx.x;
    int n = tid >> 1, h = tid & 1;
    if (n >= N) return;
    int kb = h*8;
    float out[8];
    agg_node_head(n, h, rowS, rowE, recs, xlA, xr, we, att, bias, out);
    float hh[8];
#pragma unroll
    for (int o = 0; o < 8; o++) hh[o] = lrelu(out[o], 0.1f);
    // exchange with partner lane (other head of same node)
    float hfull[HO];
#pragma unroll
    for (int o = 0; o < 8; o++) {
        float hp = __shfl_xor(hh[o], 1, 64);
        hfull[kb + o] = hh[o];
        hfull[(kb ^ 8) + o] = hp;
    }
    // layer-2 transform: this lane computes its head's 8 outputs of xl2, xr2
    float ol[8], orr[8];
#pragma unroll
    for (int jo = 0; jo < 8; jo++) {
        int j = kb + jo;
        float a = bl2[j], b = br2[j];
#pragma unroll
        for (int k = 0; k < HO; k++) { a += wl2[HO*j+k]*hfull[k]; b += wr2[HO*j+k]*hfull[k]; }
        ol[jo] = a; orr[jo] = b;
    }
    xlB[(size_t)n*2 + h] = pack_fp8x8(ol);
    float4* xr4 = (float4*)(xr + (size_t)n*HO + kb);
    xr4[0] = make_float4(orr[0], orr[1], orr[2], orr[3]);
    xr4[1] = make_float4(orr[4], orr[5], orr[6], orr[7]);
}

// layer 2: aggregate (+bias), block-reduce, write partials column-major
__global__ void __launch_bounds__(256) node_agg_l2(
    const int* __restrict__ rowS, const int* __restrict__ rowE,
    const uint2* __restrict__ recs,
    const uint2* __restrict__ xlB, const float* __restrict__ xr,
    const float* __restrict__ we, const float* __restrict__ att,
    const float* __restrict__ bias, float* __restrict__ partials, int pstride, int N)
{
    int tid = blockIdx.x * 256 + threadIdx.x;
    int n = tid >> 1, h = tid & 1;
    float out[8];
    if (n < N) {
        agg_node_head(n, h, rowS, rowE, recs, xlB, xr, we, att, bias, out);
    } else {
#pragma unroll
        for (int o = 0; o < 8; o++) out[o] = 0.f;
    }
#pragma unroll
    for (int off = 32; off >= 2; off >>= 1) {
#pragma unroll
        for (int o = 0; o < 8; o++) out[o] += __shfl_down(out[o], off, 64);
    }
    __shared__ float sm[4][2][8];
    int wave = threadIdx.x >> 6, lane = threadIdx.x & 63;
    if (lane < 2) {
#pragma unroll
        for (int o = 0; o < 8; o++) sm[wave][lane][o] = out[o];
    }
    __syncthreads();
    if (threadIdx.x < 16) {
        int hh = threadIdx.x >> 3, oo = threadIdx.x & 7;
        float t = sm[0][hh][oo] + sm[1][hh][oo] + sm[2][hh][oo] + sm[3][hh][oo];
        partials[(size_t)(hh*8 + oo) * pstride + blockIdx.x] = t;
    }
}

// parallel partials fold: one block per column, coalesced reads
__global__ void __launch_bounds__(256) k_reduce(
    const float* __restrict__ partials, int pstride, int nparts,
    float* __restrict__ pool)
{
    __shared__ float s[256];
    int c = blockIdx.x;           // column 0..15
    int t = threadIdx.x;
    const float* col = partials + (size_t)c * pstride;
    float acc = 0.f;
    for (int r = t; r < nparts; r += 256) acc += col[r];
    s[t] = acc;
    __syncthreads();
#pragma unroll
    for (int off = 128; off > 0; off >>= 1) {
        if (t < off) s[t] += s[t + off];
        __syncthreads();
    }
    if (t == 0) pool[c] = s[0];
}

// ---------------- final tail (pool[16] precomputed) ----------------
__global__ void __launch_bounds__(64) final_mlp(
    const float* __restrict__ pool, const float* __restrict__ meta,
    const float* __restrict__ sp1_w, const float* __restrict__ sp1_b,
    const float* __restrict__ sp2_w, const float* __restrict__ sp2_b,
    const float* __restrict__ me_w, const float* __restrict__ me_b,
    const float* __restrict__ fc1_w, const float* __restrict__ fc1_b,
    const float* __restrict__ fc2_w, const float* __restrict__ fc2_b,
    const float* __restrict__ fc3_w, const float* __restrict__ fc3_b,
    float* __restrict__ out)
{
    __shared__ float s1[64], zb[24], z1[24], z2[8];
    int t = threadIdx.x;
    {
        float acc = sp1_b[t];
        for (int k = 0; k < 16; k++) acc += pool[k]*sp1_w[t*16+k];
        s1[t] = lrelu(acc, 0.1f);
    }
    __syncthreads();
    if (t < 16) {
        float acc = sp2_b[t];
        for (int k = 0; k < 64; k++) acc += s1[k]*sp2_w[t*64+k];
        zb[t] = acc;
    } else if (t < 24) {
        int j = t - 16;
        float acc = me_b[j];
        for (int k = 0; k < 6; k++) acc += meta[k]*me_w[j*6+k];
        zb[t] = lrelu(acc, 0.1f);
    }
    __syncthreads();
    if (t < 24) {
        float acc = fc1_b[t];
        for (int k = 0; k < 24; k++) acc += zb[k]*fc1_w[t*24+k];
        z1[t] = lrelu(acc, 0.1f);
    }
    __syncthreads();
    if (t < 8) {
        float acc = fc2_b[t];
        for (int k = 0; k < 24; k++) acc += z1[k]*fc2_w[t*24+k];
        z2[t] = lrelu(acc, 0.1f);
    }
    __syncthreads();
    if (t == 0) {
        float z3[3]; float mxv = -1e30f;
        for (int j = 0; j < 3; j++) {
            float acc = fc3_b[j];
            for (int k = 0; k < 8; k++) acc += z2[k]*fc3_w[j*8+k];
            z3[j] = acc; mxv = fmaxf(mxv, acc);
        }
        float s = 0.f;
        for (int j = 0; j < 3; j++) { z3[j] = __expf(z3[j]-mxv); s += z3[j]; }
        for (int j = 0; j < 3; j++) out[j] = z3[j]/s;
    }
}

extern "C" void kernel_launch(void* const* d_in, const int* in_sizes, int n_in,
                              void* d_out, int out_size, void* d_ws, size_t ws_size,
                              hipStream_t stream)
{
    const float* x      = (const float*)d_in[0];
    const int*   eidx   = (const int*)  d_in[1];
    const float* eattr  = (const float*)d_in[2];
    const float* meta   = (const float*)d_in[3];
    const float* ft1_w  = (const float*)d_in[4];
    const float* ft1_b  = (const float*)d_in[5];
    const float* ft2_w  = (const float*)d_in[6];
    const float* ft2_b  = (const float*)d_in[7];
    const float* g1_wl  = (const float*)d_in[8];
    const float* g1_bl  = (const float*)d_in[9];
    const float* g1_wr  = (const float*)d_in[10];
    const float* g1_br  = (const float*)d_in[11];
    const float* g1_we  = (const float*)d_in[12];
    const float* g1_att = (const float*)d_in[13];
    const float* g1_bias= (const float*)d_in[14];
    const float* g2_wl  = (const float*)d_in[15];
    const float* g2_bl  = (const float*)d_in[16];
    const float* g2_wr  = (const float*)d_in[17];
    const float* g2_br  = (const float*)d_in[18];
    const float* g2_we  = (const float*)d_in[19];
    const float* g2_att = (const float*)d_in[20];
    const float* g2_bias= (const float*)d_in[21];
    const float* sp1_w  = (const float*)d_in[22];
    const float* sp1_b  = (const float*)d_in[23];
    const float* sp2_w  = (const float*)d_in[24];
    const float* sp2_b  = (const float*)d_in[25];
    const float* me_w   = (const float*)d_in[26];
    const float* me_b   = (const float*)d_in[27];
    const float* fc1_w  = (const float*)d_in[28];
    const float* fc1_b  = (const float*)d_in[29];
    const float* fc2_w  = (const float*)d_in[30];
    const float* fc2_b  = (const float*)d_in[31];
    const float* fc3_w  = (const float*)d_in[32];
    const float* fc3_b  = (const float*)d_in[33];
    float* out = (float*)d_out;

    const int N = in_sizes[0] / 3;
    const int E = in_sizes[2] / 2;
    const int* src = eidx;
    const int* dst = eidx + E;

    const int BN    = (N + 255) / 256;
    const int BN2   = (2*N + 255) / 256;           // agg kernels: 2 threads/node
    const int NBUCK = (N + BNODES - 1) >> BSHIFT;  // 977 (<= 1024)
    const int BP    = (E + PCHUNK - 1) / PCHUNK;   // partition blocks
    const int pstride = (BN2 + 63) & ~63;          // column-major partials stride

    // workspace layout (256B-aligned):
    char* w = (char*)d_ws;
    size_t off = 0;
    auto take = [&](size_t bytes) { size_t o = off; off += (bytes + 255) & ~(size_t)255; return o; };
    int*    rowS     = (int*)   (w + take((size_t)4*N));
    int*    rowE     = (int*)   (w + take((size_t)4*N));
    int*    bcur     = (int*)   (w + take(4096));
    float*  pool     = (float*) (w + take(64));
    float*  partials = (float*) (w + take((size_t)4*16*pstride));
    uint2*  recs     = (uint2*) (w + take((size_t)8*NBUCK*CAP2));  // padded regions
    uint2*  xlA      = (uint2*) (w + take((size_t)16*N));          // fp8 table, layer 1
    uint2*  xlB      = (uint2*) (w + take((size_t)16*N));          // fp8 table, layer 2
    float*  xr       = (float*) (w + take((size_t)64*N));          // fp32, in-place update
    // total ~= 2MB + 45MB + 4MB + 4MB + 16MB ~= 71MB

    // node features + layer-1 transforms
    node_l1<<<BN, 256, 0, stream>>>(x, ft1_w, ft1_b, ft2_w, ft2_b,
                                    g1_wl, g1_bl, g1_wr, g1_br, xlA, xr, N);
    // two-phase dst-sort into padded bucket regions (graph-only; shared by both layers)
    k_binit<<<4, 256, 0, stream>>>(bcur);
    k_part<<<BP, PT, 0, stream>>>(src, dst, eattr, bcur, recs, E);
    k_fine<<<NBUCK, 256, 0, stream>>>(bcur, recs, rowS, rowE, N);

    // ---- layer 1 (agg + act + layer-2 transform fused) ----
    node_agg_l1<<<BN2, 256, 0, stream>>>(rowS, rowE, recs, xlA, xr,
                                         g1_we, g1_att, g1_bias,
                                         g2_wl, g2_bl, g2_wr, g2_br, xlB, N);
    // ---- layer 2 ----
    node_agg_l2<<<BN2, 256, 0, stream>>>(rowS, rowE, recs, xlB, xr,
                                         g2_we, g2_att, g2_bias, partials, pstride, N);
    // ---- tail ----
    k_reduce<<<16, 256, 0, stream>>>(partials, pstride, BN2, pool);
    final_mlp<<<1, 64, 0, stream>>>(pool, meta, sp1_w, sp1_b, sp2_w, sp2_b,
                                    me_w, me_b, fc1_w, fc1_b, fc2_w, fc2_b,
                                    fc3_w, fc3_b, out);
}